// Round 14
// baseline (1263.502 us; speedup 1.0000x reference)
//
#include <hip/hip_runtime.h>
#include <hip/hip_bf16.h>
#include <hip/hip_fp16.h>
#include <stdint.h>
#include <stddef.h>

typedef unsigned long long u64;
typedef __attribute__((ext_vector_type(8))) short bf16x8;
typedef __attribute__((ext_vector_type(8))) _Float16 f16x8;
typedef __attribute__((ext_vector_type(4))) float f32x4;

// LDS XOR swizzle in 16B granules (bank-spread for b128 write + frag read)
#define SWZG(g) ((g) ^ (((g) >> 2) & 7))

// ---------------------------------------------------------------------------
// Threefry-2x32-20 (JAX), key = (0, 42)  [verified bit-exact in round 2]
// ---------------------------------------------------------------------------
__device__ __forceinline__ uint32_t rotl32(uint32_t x, int r) {
  return (x << r) | (x >> (32 - r));
}

__device__ __forceinline__ void threefry2x32(uint32_t x0, uint32_t x1,
                                             uint32_t& o0, uint32_t& o1) {
  const uint32_t k0 = 0u, k1 = 42u;
  const uint32_t k2 = k0 ^ k1 ^ 0x1BD11BDAu;
  x0 += k0; x1 += k1;
#define TF_ROUND(r) { x0 += x1; x1 = rotl32(x1, (r)); x1 ^= x0; }
  TF_ROUND(13) TF_ROUND(15) TF_ROUND(26) TF_ROUND(6)
  x0 += k1; x1 += k2 + 1u;
  TF_ROUND(17) TF_ROUND(29) TF_ROUND(16) TF_ROUND(24)
  x0 += k2; x1 += k0 + 2u;
  TF_ROUND(13) TF_ROUND(15) TF_ROUND(26) TF_ROUND(6)
  x0 += k0; x1 += k1 + 3u;
  TF_ROUND(17) TF_ROUND(29) TF_ROUND(16) TF_ROUND(24)
  x0 += k1; x1 += k2 + 4u;
  TF_ROUND(13) TF_ROUND(15) TF_ROUND(26) TF_ROUND(6)
  x0 += k2; x1 += k0 + 5u;
#undef TF_ROUND
  o0 = x0; o1 = x1;
}

__device__ __forceinline__ float gumbel_at(uint32_t i) {
  uint32_t o0, o1;
  threefry2x32(0u, i, o0, o1);
  uint32_t bits = o0 ^ o1;
  float f = __uint_as_float((bits >> 9) | 0x3F800000u) - 1.0f;  // [0,1)
  float u = fmaxf(1e-20f, f + 1e-20f);
  return -logf(-logf(u));
}

// monotonic float->uint mapping (IEEE total order for finite values)
__device__ __forceinline__ uint32_t fmono(float v) {
  uint32_t b = __float_as_uint(v);
  return (b & 0x80000000u) ? ~b : (b | 0x80000000u);
}

__device__ __forceinline__ unsigned short f2bf(float x) {
  __hip_bfloat16 h = __float2bfloat16(x);
  return *reinterpret_cast<unsigned short*>(&h);
}

__device__ __forceinline__ float bfu2f(unsigned short v) {
  __hip_bfloat16 h = *reinterpret_cast<__hip_bfloat16*>(&v);
  return __bfloat162float(h);
}

__device__ __forceinline__ unsigned short f2h(float x) {
  __half h = __float2half(x);
  return *reinterpret_cast<unsigned short*>(&h);
}

// 2-limb f16 split with scaled residual: x ~= s0 + s1/2048, err ~2^-22|x|.
// s0 forced to 0 when f16(x) would be subnormal -> denormal-mode-robust.
__device__ __forceinline__ void split2h(float x, short& s0, short& s1) {
  float f0 = 0.0f;
  unsigned short u0 = 0;
  if (fabsf(x) >= 6.2e-5f) {
    __half h0 = __float2half(x);
    f0 = __half2float(h0);
    u0 = *reinterpret_cast<unsigned short*>(&h0);
  }
  __half h1 = __float2half((x - f0) * 2048.0f);
  s0 = (short)u0;
  s1 = *reinterpret_cast<short*>(&h1);
}

// ---------------------------------------------------------------------------
// f32 SIMT GEMM (conflict-free 4+4 split tile). Used only for L1 (K=32).
// OUTMODE 2: relu+split2h -> k-tiled planes [2][N/32][M][32].
// ---------------------------------------------------------------------------
template<int BM, int BN, int BK, int THREADS, bool RELU, bool BT, bool HASBIAS,
         int OUTMODE>
__global__ __launch_bounds__(THREADS) void gemm_kernel(
    const float* __restrict__ A, const float* __restrict__ W,
    const float* __restrict__ bias, float* __restrict__ C,
    int M, int N, int K, short* __restrict__ osplit, int pitchM)
{
  __shared__ __align__(16) float As[BK][BM + 4];
  __shared__ __align__(16) float Ws[BK][BN + 4];
  constexpr int TX = BN / 8;
  constexpr int TY = BM / 8;
  static_assert(TX * TY == THREADS, "bad tiling");
  constexpr int KV = BK / 4;

  const int tid = threadIdx.x;
  const int tx = tid % TX, ty = tid / TX;
  const int row0 = blockIdx.x * BM, col0 = blockIdx.y * BN;

  float acc[8][8];
#pragma unroll
  for (int i = 0; i < 8; ++i)
#pragma unroll
    for (int j = 0; j < 8; ++j) acc[i][j] = 0.0f;

  for (int k0 = 0; k0 < K; k0 += BK) {
#pragma unroll
    for (int e = tid; e < BM * KV; e += THREADS) {
      int m = e / KV, kq = e % KV;
      float4 v = *reinterpret_cast<const float4*>(
          &A[(size_t)(row0 + m) * K + k0 + kq * 4]);
      As[kq * 4 + 0][m] = v.x; As[kq * 4 + 1][m] = v.y;
      As[kq * 4 + 2][m] = v.z; As[kq * 4 + 3][m] = v.w;
    }
    if (BT) {
#pragma unroll
      for (int e = tid; e < BN * KV; e += THREADS) {
        int c = e / KV, kq = e % KV;
        float4 v = *reinterpret_cast<const float4*>(
            &W[(size_t)(col0 + c) * K + k0 + kq * 4]);
        Ws[kq * 4 + 0][c] = v.x; Ws[kq * 4 + 1][c] = v.y;
        Ws[kq * 4 + 2][c] = v.z; Ws[kq * 4 + 3][c] = v.w;
      }
    } else {
      constexpr int CV = BN / 4;
#pragma unroll
      for (int e = tid; e < BK * CV; e += THREADS) {
        int kk = e / CV, c4 = e % CV;
        float4 v = *reinterpret_cast<const float4*>(
            &W[(size_t)(k0 + kk) * N + col0 + c4 * 4]);
        *reinterpret_cast<float4*>(&Ws[kk][c4 * 4]) = v;
      }
    }
    __syncthreads();

#pragma unroll
    for (int kk = 0; kk < BK; ++kk) {
      float a[2][4], w[2][4];
      *reinterpret_cast<float4*>(a[0]) =
          *reinterpret_cast<const float4*>(&As[kk][ty * 4]);
      *reinterpret_cast<float4*>(a[1]) =
          *reinterpret_cast<const float4*>(&As[kk][BM / 2 + ty * 4]);
      *reinterpret_cast<float4*>(w[0]) =
          *reinterpret_cast<const float4*>(&Ws[kk][tx * 4]);
      *reinterpret_cast<float4*>(w[1]) =
          *reinterpret_cast<const float4*>(&Ws[kk][BN / 2 + tx * 4]);
#pragma unroll
      for (int ih = 0; ih < 2; ++ih)
#pragma unroll
        for (int i = 0; i < 4; ++i)
#pragma unroll
          for (int jh = 0; jh < 2; ++jh)
#pragma unroll
            for (int j = 0; j < 4; ++j)
              acc[ih * 4 + i][jh * 4 + j] =
                  fmaf(a[ih][i], w[jh][j], acc[ih * 4 + i][jh * 4 + j]);
    }
    __syncthreads();
  }

#pragma unroll
  for (int ih = 0; ih < 2; ++ih)
#pragma unroll
    for (int i = 0; i < 4; ++i) {
      const int rr = row0 + ih * (BM / 2) + ty * 4 + i;
#pragma unroll
      for (int jh = 0; jh < 2; ++jh) {
        int c = col0 + jh * (BN / 2) + tx * 4;
        float4 v = make_float4(acc[ih * 4 + i][jh * 4 + 0],
                               acc[ih * 4 + i][jh * 4 + 1],
                               acc[ih * 4 + i][jh * 4 + 2],
                               acc[ih * 4 + i][jh * 4 + 3]);
        if (HASBIAS) {
          v.x += bias[c + 0]; v.y += bias[c + 1];
          v.z += bias[c + 2]; v.w += bias[c + 3];
        }
        if (RELU) {
          v.x = fmaxf(v.x, 0.f); v.y = fmaxf(v.y, 0.f);
          v.z = fmaxf(v.z, 0.f); v.w = fmaxf(v.w, 0.f);
        }
        if (OUTMODE == 2) {
          float vv[4] = {v.x, v.y, v.z, v.w};
          size_t ps = (size_t)pitchM * N;
#pragma unroll
          for (int j = 0; j < 4; ++j) {
            short s0, s1; split2h(vv[j], s0, s1);
            int cc = c + j;
            size_t o = ((size_t)(cc >> 5) * pitchM + rr) * 32 + (cc & 31);
            osplit[o] = s0; osplit[o + ps] = s1;
          }
        } else {
          *reinterpret_cast<float4*>(&C[(size_t)rr * N + c]) = v;
        }
      }
    }
}

// ---------------------------------------------------------------------------
// Pre-split weights, 2-limb f16: W [K][N] f32 -> planes [2][K/32][N][32]
// ---------------------------------------------------------------------------
__global__ __launch_bounds__(256) void presplit_w2(
    const float* __restrict__ W, short* __restrict__ out, int K, int N)
{
  const int total = K * N;
  const size_t ps = (size_t)K * N;
  for (int idx = blockIdx.x * 256 + threadIdx.x; idx < total;
       idx += gridDim.x * 256) {
    int k = idx / N, n = idx - k * N;
    short s0, s1; split2h(W[idx], s0, s1);
    size_t o = ((size_t)(k >> 5) * N + n) * 32 + (k & 31);
    out[o] = s0; out[o + ps] = s1;
  }
}

// three 768x768 matrices -> 1-plane f16 k-tiled (value-only path weights)
__global__ __launch_bounds__(256) void presplit_w1x3(
    const float* __restrict__ A, const float* __restrict__ B,
    const float* __restrict__ C,
    short* __restrict__ oA, short* __restrict__ oB, short* __restrict__ oC)
{
  const int total = 768 * 768;
  for (int idx = blockIdx.x * 256 + threadIdx.x; idx < 3 * total;
       idx += gridDim.x * 256) {
    int seg = idx / total, e = idx - seg * total;
    const float* src = (seg == 0) ? A : ((seg == 1) ? B : C);
    short* dst = (seg == 0) ? oA : ((seg == 1) ? oB : oC);
    int k = e / 768, n = e - k * 768;
    size_t o = ((size_t)(k >> 5) * 768 + n) * 32 + (k & 31);
    dst[o] = (short)f2h(src[e]);
  }
}

// ---------------------------------------------------------------------------
// Fold scores weights through W4 (fused 2-limb f16 split) + bias2.
// grid 769: blocks 0..767 -> Ws2 rows; block 768 -> bias2.
// ---------------------------------------------------------------------------
__global__ __launch_bounds__(128) void fold_ws2(
    const float* __restrict__ W4, const float* __restrict__ selw,
    short* __restrict__ Ws2s, const float* __restrict__ b4,
    float* __restrict__ bias2)
{
  const int i = blockIdx.x;
  const int k = threadIdx.x;
  if (i == 768) {
    float s = 0.0f;
    for (int d = 0; d < 768; ++d)
      s = fmaf(b4[d], selw[(size_t)k * 768 + d], s);
    bias2[k] = s;
    return;
  }
  __shared__ float w4row[768];
  for (int j = k; j < 768; j += 128) w4row[j] = W4[(size_t)i * 768 + j];
  __syncthreads();
  float acc = 0.0f;
  const float* sr = selw + (size_t)k * 768;
#pragma unroll 8
  for (int j = 0; j < 768; ++j) acc = fmaf(w4row[j], sr[j], acc);
  short s0, s1; split2h(acc, s0, s1);
  const size_t ps = (size_t)768 * 128;
  size_t o = ((size_t)(i >> 5) * 128 + k) * 32 + (i & 31);
  Ws2s[o] = s0; Ws2s[o + ps] = s1;
}

// ---------------------------------------------------------------------------
// MFMA GEMM, plane-input only.
// LIMBS=2: f16 2-limb scaled-residual, 3 MFMAs/ktile, dual accumulator
//          (acc0 + accX*2^-11) — err ~2^-22, selection-safe.
// LIMBS=1: plain f16 (plane 0 of A), 1 MFMA/ktile (value-only path).
// A planes [LIMBS][kfull/32][apitch][32]; optional rowmap gather.
// MODE 0: relu(+bias) -> split2h planes, pitch opitch, row offset r0
// MODE 1: (+bias if nonnull, opt RELUF) -> f32 rows [M][N]
// MODE 2: y<gy-1 -> pf bf16 (+bias, row offset r0); y==gy-1 -> scores f32
//         (+bias2), weights W2g   (Path B combo)
// MODE 4: (+bias) -> bf16 rows [M][N]
// MODE 5: relu(+bias) -> 1-plane f16 k-tiled, pitch opitch
// MODE 7: relu(+bias) -> split2h planes (pitch opitch, local row) AND
//         limb0 -> persistent 1-plane f16, global pitch 65536, offset r0
//         (pfout reinterpreted as short*).
// ---------------------------------------------------------------------------
template<int MODE, int LIMBS, bool RELUF>
__global__ __launch_bounds__(256) void mfma_gemm(
    const void* __restrict__ Agv, const short* __restrict__ Wg,
    const short* __restrict__ W2g,
    const float* __restrict__ bias, const float* __restrict__ bias2,
    short* __restrict__ out_split, unsigned short* __restrict__ pfout,
    float* __restrict__ fout, int M, int N, int K, int r0,
    const int* __restrict__ rowmap,
    int kbase, int kfull, int apitch, int opitch)
{
  __shared__ __align__(16) short Als[LIMBS][128 * 32];
  __shared__ __align__(16) short Bls[LIMBS][128 * 32];

  const int tid = threadIdx.x;
  const int lane = tid & 63;
  const int wid = tid >> 6;
  const int wm = wid >> 1, wn = wid & 1;
  const int fr = lane & 15, kg = lane >> 4;
  const int row0 = blockIdx.x * 128;
  const bool SC = (MODE == 2) && ((int)blockIdx.y == (int)gridDim.y - 1);
  const short* Wsrc = SC ? W2g : Wg;
  const int Nw = SC ? 128 : N;
  const int col0 = SC ? 0 : blockIdx.y * 128;
  const short* Ag = (const short*)Agv;
  const size_t planeA = (size_t)apitch * kfull;
  const size_t planeW = (size_t)Nw * kfull;
  const int kb = kbase >> 5;

  const int su0 = tid, su1 = tid + 256;
  int ar0 = row0 + (su0 >> 2), ar1 = row0 + (su1 >> 2);
  if (rowmap) { ar0 = rowmap[ar0]; ar1 = rowmap[ar1]; }
  const int br0 = col0 + (su0 >> 2), br1 = col0 + (su1 >> 2);
  const int acol0 = (su0 & 3) * 8, acol1 = (su1 & 3) * 8;
  const int sb0 = SWZG(su0) * 8, sb1 = SWZG(su1) * 8;  // swizzled LDS bases

  f32x4 acc0[4][4];
  f32x4 accX[4][4];
#pragma unroll
  for (int i = 0; i < 4; ++i)
#pragma unroll
    for (int j = 0; j < 4; ++j) { acc0[i][j] = (f32x4)0.0f; accX[i][j] = (f32x4)0.0f; }

  const int nk = K >> 5;
  bf16x8 stA[LIMBS][2], stB[LIMBS][2];

  // initial prefetch (kt = 0)
#pragma unroll
  for (int s = 0; s < LIMBS; ++s) {
    const short* pa = Ag + (size_t)s * planeA + (size_t)kb * apitch * 32;
    const short* pb = Wsrc + (size_t)s * planeW + (size_t)kb * Nw * 32;
    stA[s][0] = *(const bf16x8*)(pa + (size_t)ar0 * 32 + acol0);
    stA[s][1] = *(const bf16x8*)(pa + (size_t)ar1 * 32 + acol1);
    stB[s][0] = *(const bf16x8*)(pb + (size_t)br0 * 32 + acol0);
    stB[s][1] = *(const bf16x8*)(pb + (size_t)br1 * 32 + acol1);
  }

  for (int kt = 0; kt < nk; ++kt) {
    __syncthreads();  // previous tile reads complete
    // --- write LDS (swizzled) ---
#pragma unroll
    for (int s = 0; s < LIMBS; ++s) {
      *(bf16x8*)(&Als[s][sb0]) = stA[s][0];
      *(bf16x8*)(&Als[s][sb1]) = stA[s][1];
      *(bf16x8*)(&Bls[s][sb0]) = stB[s][0];
      *(bf16x8*)(&Bls[s][sb1]) = stB[s][1];
    }
    // --- prefetch next tile ---
    if (kt + 1 < nk) {
#pragma unroll
      for (int s = 0; s < LIMBS; ++s) {
        const short* pa = Ag + (size_t)s * planeA +
                          (size_t)(kb + kt + 1) * apitch * 32;
        const short* pb = Wsrc + (size_t)s * planeW +
                          (size_t)(kb + kt + 1) * Nw * 32;
        stA[s][0] = *(const bf16x8*)(pa + (size_t)ar0 * 32 + acol0);
        stA[s][1] = *(const bf16x8*)(pa + (size_t)ar1 * 32 + acol1);
        stB[s][0] = *(const bf16x8*)(pb + (size_t)br0 * 32 + acol0);
        stB[s][1] = *(const bf16x8*)(pb + (size_t)br1 * 32 + acol1);
      }
    }
    __syncthreads();  // LDS writes visible

    if (LIMBS == 2) {
      f16x8 a0[4], b0[4];
#pragma unroll
      for (int t = 0; t < 4; ++t) {
        const int ga = ((wm * 64 + t * 16 + fr) << 2) | kg;
        const int gb = ((wn * 64 + t * 16 + fr) << 2) | kg;
        a0[t] = *(const f16x8*)(&Als[0][SWZG(ga) * 8]);
        b0[t] = *(const f16x8*)(&Bls[0][SWZG(gb) * 8]);
      }
#pragma unroll
      for (int mt = 0; mt < 4; ++mt)
#pragma unroll
        for (int nt = 0; nt < 4; ++nt)
          acc0[mt][nt] = __builtin_amdgcn_mfma_f32_16x16x32_f16(
              a0[mt], b0[nt], acc0[mt][nt], 0, 0, 0);
      f16x8 x1[4];
#pragma unroll
      for (int t = 0; t < 4; ++t) {
        const int gb = ((wn * 64 + t * 16 + fr) << 2) | kg;
        x1[t] = *(const f16x8*)(&Bls[LIMBS - 1][SWZG(gb) * 8]);
      }
#pragma unroll
      for (int mt = 0; mt < 4; ++mt)
#pragma unroll
        for (int nt = 0; nt < 4; ++nt)
          accX[mt][nt] = __builtin_amdgcn_mfma_f32_16x16x32_f16(
              a0[mt], x1[nt], accX[mt][nt], 0, 0, 0);
#pragma unroll
      for (int t = 0; t < 4; ++t) {
        const int ga = ((wm * 64 + t * 16 + fr) << 2) | kg;
        x1[t] = *(const f16x8*)(&Als[LIMBS - 1][SWZG(ga) * 8]);
      }
#pragma unroll
      for (int mt = 0; mt < 4; ++mt)
#pragma unroll
        for (int nt = 0; nt < 4; ++nt)
          accX[mt][nt] = __builtin_amdgcn_mfma_f32_16x16x32_f16(
              x1[mt], b0[nt], accX[mt][nt], 0, 0, 0);
    } else {
      f16x8 a0[4], b0[4];
#pragma unroll
      for (int t = 0; t < 4; ++t) {
        const int ga = ((wm * 64 + t * 16 + fr) << 2) | kg;
        const int gb = ((wn * 64 + t * 16 + fr) << 2) | kg;
        a0[t] = *(const f16x8*)(&Als[0][SWZG(ga) * 8]);
        b0[t] = *(const f16x8*)(&Bls[0][SWZG(gb) * 8]);
      }
#pragma unroll
      for (int mt = 0; mt < 4; ++mt)
#pragma unroll
        for (int nt = 0; nt < 4; ++nt)
          acc0[mt][nt] = __builtin_amdgcn_mfma_f32_16x16x32_f16(
              a0[mt], b0[nt], acc0[mt][nt], 0, 0, 0);
    }
  }

  // epilogue: C frag mapping col = lane&15, row = (lane>>4)*4 + r  [m89]
  const size_t psO = (size_t)opitch * N;
#pragma unroll
  for (int mt = 0; mt < 4; ++mt)
#pragma unroll
    for (int nt = 0; nt < 4; ++nt)
#pragma unroll
      for (int r = 0; r < 4; ++r) {
        int row = row0 + wm * 64 + mt * 16 + kg * 4 + r;
        int col = col0 + wn * 64 + nt * 16 + fr;
        float x = acc0[mt][nt][r];
        if (LIMBS == 2) x += accX[mt][nt][r] * 4.8828125e-4f;  // 2^-11
        if (MODE == 2) {
          if (SC) {
            fout[(size_t)row * 128 + col] = x + bias2[col];
          } else {
            pfout[(size_t)(r0 + row) * 768 + col] = f2bf(x + bias[col]);
          }
        } else if (MODE == 1) {
          if (bias) x += bias[col];
          if (RELUF) x = fmaxf(x, 0.0f);
          fout[(size_t)row * N + col] = x;
        } else if (MODE == 4) {
          pfout[(size_t)row * N + col] = f2bf(x + bias[col]);
        } else if (MODE == 5) {
          x = fmaxf(x + bias[col], 0.0f);
          size_t o = ((size_t)(col >> 5) * opitch + row) * 32 + (col & 31);
          out_split[o] = (short)f2h(x);
        } else if (MODE == 7) {
          x = fmaxf(x + bias[col], 0.0f);
          short s0, s1; split2h(x, s0, s1);
          size_t o = ((size_t)(col >> 5) * opitch + row) * 32 + (col & 31);
          out_split[o] = s0; out_split[o + psO] = s1;
          size_t op = ((size_t)(col >> 5) * 65536 + (r0 + row)) * 32 + (col & 31);
          ((short*)pfout)[op] = s0;
        } else {  // MODE 0
          x = fmaxf(x + bias[col], 0.0f);
          short s0, s1; split2h(x, s0, s1);
          size_t o = ((size_t)(col >> 5) * opitch + (r0 + row)) * 32 + (col & 31);
          out_split[o] = s0; out_split[o + psO] = s1;
        }
      }
}

// ---------------------------------------------------------------------------
// scores [rows][128] f32 -> sgT[b][k][m] with fused Gumbel noise.
// grid (rows/32, 4), block (32, 8)
// ---------------------------------------------------------------------------
__global__ __launch_bounds__(256) void gumbel_transpose(
    const float* __restrict__ sc, float* __restrict__ sgT, int r0)
{
  __shared__ float tile[32][33];
  const int lm0 = blockIdx.x * 32;
  const int k0 = blockIdx.y * 32;
  const int tx = threadIdx.x, ty = threadIdx.y;
#pragma unroll
  for (int rr = ty; rr < 32; rr += 8)
    tile[rr][tx] = sc[(size_t)(lm0 + rr) * 128 + k0 + tx];
  __syncthreads();
#pragma unroll
  for (int rr = ty; rr < 32; rr += 8) {
    int k = k0 + rr;
    int gm = r0 + lm0 + tx;
    uint32_t idx = ((uint32_t)(gm >> 13) << 20) | ((uint32_t)k << 13) |
                   (uint32_t)(gm & 8191);
    sgT[idx] = tile[tx][rr] + gumbel_at(idx);
  }
}

// ---------------------------------------------------------------------------
// Per-(b,k) top-32 of sgT row — register-resident incremental tournament.
// ---------------------------------------------------------------------------
__global__ __launch_bounds__(256) void top_candidates(
    const float* __restrict__ sgT, u64* __restrict__ cand)
{
  const int q = blockIdx.x;
  const int tid = threadIdx.x;
  const int lane = tid & 63, wid = tid >> 6;
  __shared__ u64 wb[4];
  u64 pr[32];
  const float4* row4 = reinterpret_cast<const float4*>(sgT + (size_t)q * 8192);
#pragma unroll
  for (int j = 0; j < 8; ++j) {
    float4 v = row4[tid + j * 256];
    const int mb = (tid + j * 256) * 4;
    pr[j * 4 + 0] = ((u64)fmono(v.x) << 13) | (u64)(8191 - (mb + 0));
    pr[j * 4 + 1] = ((u64)fmono(v.y) << 13) | (u64)(8191 - (mb + 1));
    pr[j * 4 + 2] = ((u64)fmono(v.z) << 13) | (u64)(8191 - (mb + 2));
    pr[j * 4 + 3] = ((u64)fmono(v.w) << 13) | (u64)(8191 - (mb + 3));
  }
  u64 lmax = 0;
#pragma unroll
  for (int r = 0; r < 32; ++r) if (pr[r] > lmax) lmax = pr[r];

  for (int it = 0; it < 32; ++it) {
    u64 loc = lmax;
#pragma unroll
    for (int off = 32; off; off >>= 1) {
      u64 o = __shfl_down(loc, off);
      if (o > loc) loc = o;
    }
    if (lane == 0) wb[wid] = loc;
    __syncthreads();
    u64 w01 = (wb[0] > wb[1]) ? wb[0] : wb[1];
    u64 w23 = (wb[2] > wb[3]) ? wb[2] : wb[3];
    u64 winner = (w01 > w23) ? w01 : w23;
    __syncthreads();
    if (tid == 0) cand[(size_t)q * 32 + it] = winner;
    const int wmm = 8191 - (int)(winner & 0x1FFFull);
    if (((wmm >> 2) & 255) == tid) {
      const int orr = ((wmm >> 10) << 2) | (wmm & 3);
#pragma unroll
      for (int r = 0; r < 32; ++r) if (r == orr) pr[r] = 0;
      lmax = 0;
#pragma unroll
      for (int r = 0; r < 32; ++r) if (pr[r] > lmax) lmax = pr[r];
    }
  }
}

// ---------------------------------------------------------------------------
// Sequential resolve from LDS-resident candidate lists. grid (8), block 64.
// ---------------------------------------------------------------------------
__global__ __launch_bounds__(64) void resolve_kernel(
    const u64* __restrict__ cand, const float* __restrict__ sgT,
    int* __restrict__ sel)
{
  const int b = blockIdx.x;
  const int lane = threadIdx.x;
  __shared__ u64 candL[4096];
  __shared__ uint32_t avail[256];
  for (int j = lane; j < 4096; j += 64) candL[j] = cand[(size_t)b * 4096 + j];
#pragma unroll
  for (int j = lane; j < 256; j += 64) avail[j] = 0xFFFFFFFFu;
  __syncthreads();

  for (int k = 0; k < 128; ++k) {
    u64 c = (lane < 32) ? candL[k * 32 + lane] : 0ull;
    int m = 8191 - (int)(c & 0x1FFFull);
    bool av = (lane < 32) && ((avail[m >> 5] >> (m & 31)) & 1u);
    u64 bal = __ballot(av);
    int pick;
    if (bal) {
      int j = __builtin_ctzll(bal);
      pick = __shfl(m, j);
    } else {
      u64 best = 0ull;
      const float* row = sgT + (size_t)(b * 128 + k) * 8192;
      for (int mm = lane; mm < 8192; mm += 64) {
        if ((avail[mm >> 5] >> (mm & 31)) & 1u) {
          u64 p = ((u64)fmono(row[mm]) << 13) | (u64)(8191 - mm);
          if (p > best) best = p;
        }
      }
#pragma unroll
      for (int off = 32; off; off >>= 1) {
        u64 o = __shfl_down(best, off);
        if (o > best) best = o;
      }
      best = __shfl(best, 0);
      pick = 8191 - (int)(best & 0x1FFFull);
    }
    if (lane == 0) {
      sel[b * 128 + k] = pick;
      avail[pick >> 5] &= ~(1u << (pick & 31));
    }
    __syncthreads();
  }
}

// ---------------------------------------------------------------------------
// KNN: d2 to 8192 points (LDS), 16 argmin passes.
// POOL=true: fused max-pool from full pf (bf16), split2h planes out (Path B).
// POOL=false: write neighbor indices only (Path A).
// ---------------------------------------------------------------------------
template<bool POOL>
__global__ __launch_bounds__(256) void knn_kernel(
    const float* __restrict__ coords,
    const __hip_bfloat16* __restrict__ pf,
    const int* __restrict__ sel_idx,
    short* __restrict__ pooled_s,
    int* __restrict__ nbrs_g)
{
  const int q = blockIdx.x;
  const int b = q >> 7;
  const int tid = threadIdx.x;
  const int lane = tid & 63, wid = tid >> 6;
  __shared__ float d2s[8192];
  __shared__ int nbrs[16];
  __shared__ u64 wb[4];

  const int sidx = sel_idx[q];
  const float* cbase = coords + (size_t)b * 8192 * 5;
  const float cx = cbase[sidx * 5 + 1];
  const float cy = cbase[sidx * 5 + 2];
  const float cz = cbase[sidx * 5 + 3];
  const float ss = cx * cx + cy * cy + cz * cz;

  for (int j = 0; j < 32; ++j) {
    int m = tid + j * 256;
    float px = cbase[m * 5 + 1], py = cbase[m * 5 + 2], pz = cbase[m * 5 + 3];
    d2s[m] = ss + (px * px + py * py + pz * pz)
               - 2.0f * (cx * px + cy * py + cz * pz);
  }
  __syncthreads();

  for (int it = 0; it < 16; ++it) {
    u64 loc = ~0ull;
    for (int j = 0; j < 32; ++j) {
      int m = tid + j * 256;
      u64 p = ((u64)fmono(d2s[m]) << 13) | (u64)m;
      if (p < loc) loc = p;
    }
#pragma unroll
    for (int off = 32; off; off >>= 1) {
      u64 o = __shfl_down(loc, off);
      if (o < loc) loc = o;
    }
    if (lane == 0) wb[wid] = loc;
    __syncthreads();
    if (tid == 0) {
      u64 best = wb[0];
      if (wb[1] < best) best = wb[1];
      if (wb[2] < best) best = wb[2];
      if (wb[3] < best) best = wb[3];
      int m = (int)(best & 0x1FFFull);
      nbrs[it] = m;
      d2s[m] = __uint_as_float(0x7F800000u);
    }
    __syncthreads();
  }

  if (POOL) {
    const size_t ps = (size_t)1024 * 768;
    for (int d = tid; d < 768; d += 256) {
      float mx = -__uint_as_float(0x7F800000u);
#pragma unroll
      for (int it = 0; it < 16; ++it) {
        float v = __bfloat162float(pf[((size_t)b * 8192 + nbrs[it]) * 768 + d]);
        mx = fmaxf(mx, v);
      }
      short s0, s1; split2h(mx, s0, s1);
      size_t o = ((size_t)(d >> 5) * 1024 + q) * 32 + (d & 31);
      pooled_s[o] = s0; pooled_s[o + ps] = s1;
    }
  } else {
    if (tid < 16) nbrs_g[q * 16 + tid] = nbrs[tid];
  }
}

// ---------------------------------------------------------------------------
// Path A helpers
// ---------------------------------------------------------------------------
__global__ __launch_bounds__(256) void build_rowlist(
    const int* __restrict__ sel, const int* __restrict__ nbrs_g,
    int* __restrict__ rowlist)
{
  int j = blockIdx.x * 256 + threadIdx.x;
  if (j < 1024) {
    rowlist[j] = (j >> 7) * 8192 + sel[j];
  } else if (j < 17408) {
    int jj = j - 1024;
    int q = jj >> 4;
    rowlist[j] = (q >> 7) * 8192 + nbrs_g[jj];
  }
}

// pooled (1-plane f16 k-tiled) from pf_sub neighbor rows. grid (1024).
__global__ __launch_bounds__(256) void pool_from_sub(
    const unsigned short* __restrict__ pf_sub, short* __restrict__ pooled_s)
{
  const int q = blockIdx.x;
  const int tid = threadIdx.x;
  const unsigned short* base = pf_sub + (size_t)(1024 + q * 16) * 768;
  for (int d = tid; d < 768; d += 256) {
    float mx = -__uint_as_float(0x7F800000u);
#pragma unroll
    for (int it = 0; it < 16; ++it)
      mx = fmaxf(mx, bfu2f(base[(size_t)it * 768 + d]));
    size_t o = ((size_t)(d >> 5) * 1024 + q) * 32 + (d & 31);
    pooled_s[o] = (short)f2h(mx);
  }
}

// ---------------------------------------------------------------------------
// Parallel finalize.
// ---------------------------------------------------------------------------
__global__ __launch_bounds__(128) void rank_cent(
    const float* __restrict__ coords, const int* __restrict__ sel_idx,
    int* __restrict__ rank_g, float* __restrict__ out)
{
  const int b = blockIdx.x;
  const int tid = threadIdx.x;
  __shared__ float tvals[128];
  const float* cbase = coords + (size_t)b * 8192 * 5;
  const int q = (b << 7) + tid;
  const int sidx = sel_idx[q];
  tvals[tid] = cbase[sidx * 5 + 4];
  __syncthreads();
  float t = tvals[tid];
  int r = 0;
#pragma unroll 8
  for (int j = 0; j < 128; ++j) {
    float tj = tvals[j];
    r += (tj < t || (tj == t && j < tid)) ? 1 : 0;
  }
  rank_g[q] = r;
  float* cent = out + 786432;
  float* mask = out + 786432 + 4096;
  cent[((b << 7) + r) * 4 + 0] = cbase[sidx * 5 + 1];
  cent[((b << 7) + r) * 4 + 1] = cbase[sidx * 5 + 2];
  cent[((b << 7) + r) * 4 + 2] = cbase[sidx * 5 + 3];
  cent[((b << 7) + r) * 4 + 3] = cbase[sidx * 5 + 4];
  mask[q] = 1.0f;
}

__global__ __launch_bounds__(192) void token_write(
    const unsigned short* __restrict__ feat, const float* __restrict__ agg,
    const int* __restrict__ rank_g, const int* __restrict__ selmap,
    float* __restrict__ out)
{
  const int b = blockIdx.x, i = blockIdx.y;
  const int q = (b << 7) + i;
  const int tid = threadIdx.x;
  const int r = rank_g[q];
  const unsigned short* src =
      selmap ? feat + ((size_t)b * 8192 + selmap[q]) * 768
             : feat + (size_t)q * 768;
  const float* asrc = agg + (size_t)q * 768;
  float* dst = out + ((size_t)(b << 7) + r) * 768;
  for (int d = tid; d < 768; d += 192)
    dst[d] = bfu2f(src[d]) + asrc[d];
}

// ---------------------------------------------------------------------------
// host launcher — Path A' (deferred pf, 1-plane persistent h3, fits ~224MB)
// when ws allows, else Path B (round-13 proven).
// ---------------------------------------------------------------------------
extern "C" void kernel_launch(void* const* d_in, const int* in_sizes, int n_in,
                              void* d_out, int out_size, void* d_ws, size_t ws_size,
                              hipStream_t stream) {
  const float* coords = (const float*)d_in[0];
  const float* feats  = (const float*)d_in[1];
  const float* W1 = (const float*)d_in[2];  const float* b1 = (const float*)d_in[3];
  const float* W2 = (const float*)d_in[4];  const float* b2 = (const float*)d_in[5];
  const float* W3 = (const float*)d_in[6];  const float* b3 = (const float*)d_in[7];
  const float* W4 = (const float*)d_in[8];  const float* b4 = (const float*)d_in[9];
  const float* selw = (const float*)d_in[10];
  const float* nW1 = (const float*)d_in[11]; const float* nb1 = (const float*)d_in[12];
  const float* nW2 = (const float*)d_in[13]; const float* nb2 = (const float*)d_in[14];
  float* out = (float*)d_out;
  char* ws = (char*)d_ws;
  dim3 blk(256);

  // ---------------- Path A' layout (persistent ~173.7 MB) ----------------
  size_t a = 0;
  short* h3p0  = (short*)(ws + a);          a += (size_t)65536 * 768 * 2;   // 96MB, 1-plane f16
  float* sgTa  = (float*)(ws + a);          a += (size_t)8 * 128 * 8192 * 4; // 32MB
  short* W2sa  = (short*)(ws + a);          a += (size_t)2 * 256 * 512 * 2;
  short* W3sa  = (short*)(ws + a);          a += (size_t)2 * 512 * 768 * 2;
  short* W4sa  = (short*)(ws + a);          a += (size_t)768 * 768 * 2;      // f16 1-plane
  short* Ws2sa = (short*)(ws + a);          a += (size_t)2 * 768 * 128 * 2;
  short* nW1sa = (short*)(ws + a);          a += (size_t)768 * 768 * 2;
  short* nW2sa = (short*)(ws + a);          a += (size_t)768 * 768 * 2;
  float* bias2a = (float*)(ws + a);         a += 512;
  unsigned short* pf_sub = (unsigned short*)(ws + a); a += (size_t)17408 * 768 * 2;
  short* pooled_a = (short*)(ws + a);       a += (size_t)1024 * 768 * 2;
  short* t1sa  = (short*)(ws + a);          a += (size_t)1024 * 768 * 2;
  float* agga  = (float*)(ws + a);          a += (size_t)1024 * 768 * 4;
  u64*   canda = (u64*)(ws + a);            a += (size_t)1024 * 32 * 8;
  int*   sela  = (int*)(ws + a);            a += 4096;
  int*   nbrs_g = (int*)(ws + a);           a += (size_t)1024 * 16 * 4;
  int*   rowlist = (int*)(ws + a);          a += (size_t)17408 * 4;
  int*   rank_a = (int*)(ws + a);           a += 4096;
  a = (a + 255) & ~(size_t)255;
  const size_t tmpA = a;

  // chunk temps: h1s 1024 B/row, h2s 2048 B/row, h3c (2-limb) 3072 B/row.
  // scc (512 B/row) aliases h1s (dead after L2). Total 6144 B/row.
  int McA = 0;
  {
    const int mc[3] = {8192, 4096, 2048};
    for (int ci = 0; ci < 3; ++ci)
      if (tmpA + (size_t)6144 * mc[ci] <= ws_size) { McA = mc[ci]; break; }
  }

  if (McA) {
    // =========================== PATH A' ===========================
    short* h1s = (short*)(ws + tmpA);
    short* h2s = (short*)(ws + tmpA + (size_t)1024 * McA);
    short* h3c = (short*)(ws + tmpA + (size_t)3072 * McA);
    float* scc = (float*)h1s;  // alias: h1s dead after L2

    fold_ws2<<<dim3(769), dim3(128), 0, stream>>>(W4, selw, Ws2sa, b4, bias2a);
    presplit_w2<<<256, blk, 0, stream>>>(W2, W2sa, 256, 512);
    presplit_w2<<<256, blk, 0, stream>>>(W3, W3sa, 512, 768);
    presplit_w1x3<<<512, blk, 0, stream>>>(W4, nW1, nW2, W4sa, nW1sa, nW2sa);

    for (int r0 = 0; r0 < 65536; r0 += McA) {
      const int cm = McA;
      gemm_kernel<128,128,16,256,true ,false,true ,2>
        <<<dim3(cm/128, 2), blk, 0, stream>>>(feats + (size_t)r0 * 32, W1, b1,
                                              nullptr, cm, 256, 32, h1s, cm);
      mfma_gemm<0,2,false><<<dim3(cm/128, 4), blk, 0, stream>>>(
          h1s, W2sa, nullptr, b2, nullptr, h2s, nullptr, nullptr,
          cm, 512, 256, 0, nullptr, 0, 256, cm, cm);
      // L3: chunk 2-limb planes (for scores) + persistent limb0 plane
      mfma_gemm<7,2,false><<<dim3(cm/128, 6), blk, 0, stream>>>(
          h2s, W3sa, nullptr, b3, nullptr, h3c,
          (unsigned short*)h3p0, nullptr,
          cm, 768, 512, r0, nullptr, 0, 512, cm, cm);
      // scores from chunk-local 2-limb h3 (L2/L3-hot)
      mfma_gemm<1,2,false><<<dim3(cm/128, 1), blk, 0, stream>>>(
          h3c, Ws2sa, nullptr, bias2a, nullptr, nullptr, nullptr, scc,
          cm, 128, 768, 0, nullptr, 0, 768, cm, 0);
      gumbel_transpose<<<dim3(cm/32, 4), dim3(32, 8), 0, stream>>>(
          scc, sgTa, r0);
    }

    top_candidates<<<dim3(1024), blk, 0, stream>>>(sgTa, canda);
    resolve_kernel<<<dim3(8), dim3(64), 0, stream>>>(canda, sgTa, sela);
    knn_kernel<false><<<dim3(1024), blk, 0, stream>>>(
        coords, nullptr, sela, nullptr, nbrs_g);
    build_rowlist<<<dim3(68), blk, 0, stream>>>(sela, nbrs_g, rowlist);
    // gathered L4 from persistent h3 limb0 (f16), 1-limb value path
    mfma_gemm<4,1,false><<<dim3(136, 6), blk, 0, stream>>>(
        h3p0, W4sa, nullptr, b4, nullptr, nullptr, pf_sub, nullptr,
        17408, 768, 768, 0, rowlist, 0, 768, 65536, 0);
    pool_from_sub<<<dim3(1024), blk, 0, stream>>>(pf_sub, pooled_a);
    mfma_gemm<5,1,false><<<dim3(8, 6), blk, 0, stream>>>(
        pooled_a, nW1sa, nullptr, nb1, nullptr, t1sa, nullptr, nullptr,
        1024, 768, 768, 0, nullptr, 0, 768, 1024, 1024);
    mfma_gemm<1,1,false><<<dim3(8, 6), blk, 0, stream>>>(
        t1sa, nW2sa, nullptr, nb2, nullptr, nullptr, nullptr, agga,
        1024, 768, 768, 0, nullptr, 0, 768, 1024, 0);
    rank_cent<<<dim3(8), dim3(128), 0, stream>>>(coords, sela, rank_a, out);
    token_write<<<dim3(8, 128), dim3(192), 0, stream>>>(
        pf_sub, agga, rank_a, nullptr, out);
    return;
  }

  // =========================== PATH B (fallback, round-13 proven) ==========
  size_t off = 0;
  unsigned short* pf = (unsigned short*)(ws + off); off += (size_t)65536 * 768 * 2;
  float* sgT   = (float*)(ws + off);  off += (size_t)8 * 128 * 8192 * 4;
  short* W2s   = (short*)(ws + off);  off += (size_t)2 * 256 * 512 * 2;
  short* W3s   = (short*)(ws + off);  off += (size_t)2 * 512 * 768 * 2;
  short* W4s   = (short*)(ws + off);  off += (size_t)2 * 768 * 768 * 2;
  short* Ws2s  = (short*)(ws + off);  off += (size_t)2 * 768 * 128 * 2;
  short* nW1s  = (short*)(ws + off);  off += (size_t)2 * 768 * 768 * 2;
  short* nW2s  = (short*)(ws + off);  off += (size_t)2 * 768 * 768 * 2;
  float* bias2 = (float*)(ws + off);  off += 512;
  short* pooled_s = (short*)(ws + off); off += (size_t)2 * 1024 * 768 * 2;
  short* t1s   = (short*)(ws + off);  off += (size_t)2 * 1024 * 768 * 2;
  float* agg   = (float*)(ws + off);  off += (size_t)1024 * 768 * 4;
  u64*   cand  = (u64*)(ws + off);    off += (size_t)1024 * 32 * 8;
  int*   sel   = (int*)(ws + off);    off += 4096;
  int*   rank_g = (int*)(ws + off);   off += 4096;
  off = (off + 255) & ~(size_t)255;
  const size_t tmp_off = off;

  int Mc = 512;
  const int mcand[6] = {16384, 8192, 4096, 2048, 1024, 512};
  for (int ci = 0; ci < 6; ++ci) {
    if (tmp_off + (size_t)5120 * mcand[ci] <= ws_size) { Mc = mcand[ci]; break; }
  }
  short* tA = (short*)(ws + tmp_off);                       // h2s (2048 B/row)
  short* tB = (short*)(ws + tmp_off + (size_t)2048 * Mc);   // h1s/h3s (3072 B/row)
  float* scc = (float*)tA;  // alias: h2s dead after L3

  fold_ws2<<<dim3(769), dim3(128), 0, stream>>>(W4, selw, Ws2s, b4, bias2);
  presplit_w2<<<256, blk, 0, stream>>>(W2, W2s, 256, 512);
  presplit_w2<<<256, blk, 0, stream>>>(W3, W3s, 512, 768);
  presplit_w2<<<256, blk, 0, stream>>>(W4, W4s, 768, 768);
  presplit_w2<<<256, blk, 0, stream>>>(nW1, nW1s, 768, 768);
  presplit_w2<<<256, blk, 0, stream>>>(nW2, nW2s, 768, 768);

  for (int r0 = 0; r0 < 65536; r0 += Mc) {
    const int cm = (65536 - r0 < Mc) ? (65536 - r0) : Mc;
    short* h1s = tB;
    short* h2s = tA;
    short* h3s = tB;  // alias: h1s dead after L2
    gemm_kernel<128,128,16,256,true ,false,true ,2>
      <<<dim3(cm/128, 2), blk, 0, stream>>>(feats + (size_t)r0 * 32, W1, b1,
                                            nullptr, cm, 256, 32, h1s, cm);
    mfma_gemm<0,2,false><<<dim3(cm/128, 4), blk, 0, stream>>>(
        h1s, W2s, nullptr, b2, nullptr, h2s, nullptr, nullptr,
        cm, 512, 256, 0, nullptr, 0, 256, cm, cm);
    mfma_gemm<0,2,false><<<dim3(cm/128, 6), blk, 0, stream>>>(
        h2s, W3s, nullptr, b3, nullptr, h3s, nullptr, nullptr,
        cm, 768, 512, 0, nullptr, 0, 512, cm, cm);
    mfma_gemm<2,2,false><<<dim3(cm/128, 7), blk, 0, stream>>>(
        h3s, W4s, Ws2s, b4, bias2, nullptr, pf, scc,
        cm, 768, 768, r0, nullptr, 0, 768, cm, 0);
    gumbel_transpose<<<dim3(cm/32, 4), dim3(32, 8), 0, stream>>>(scc, sgT, r0);
  }

  top_candidates<<<dim3(1024), blk, 0, stream>>>(sgT, cand);
  resolve_kernel<<<dim3(8), dim3(64), 0, stream>>>(cand, sgT, sel);
  knn_kernel<true ><<<dim3(1024), blk, 0, stream>>>(
      coords, (const __hip_bfloat16*)pf, sel, pooled_s, nullptr);
  mfma_gemm<0,2,false><<<dim3(8, 6), blk, 0, stream>>>(
      pooled_s, nW1s, nullptr, nb1, nullptr, t1s, nullptr, nullptr,
      1024, 768, 768, 0, nullptr, 0, 768, 1024, 1024);
  mfma_gemm<1,2,false><<<dim3(8, 6), blk, 0, stream>>>(
      t1s, nW2s, nullptr, nb2, nullptr, nullptr, nullptr, agg,
      1024, 768, 768, 0, nullptr, 0, 768, 1024, 0);
  rank_cent<<<dim3(8), dim3(128), 0, stream>>>(coords, sel, rank_g, out);
  token_write<<<dim3(8, 128), dim3(192), 0, stream>>>(
      pf, agg, rank_g, sel, out);
}

// Round 15
// 1234.190 us; speedup vs baseline: 1.0238x; 1.0238x over previous
//
#include <hip/hip_runtime.h>
#include <hip/hip_bf16.h>
#include <hip/hip_fp16.h>
#include <stdint.h>
#include <stddef.h>

typedef unsigned long long u64;
typedef __attribute__((ext_vector_type(8))) short bf16x8;
typedef __attribute__((ext_vector_type(8))) _Float16 f16x8;
typedef __attribute__((ext_vector_type(4))) float f32x4;

// LDS XOR swizzle in 16B granules (bank-spread for b128 write + frag read)
#define SWZG(g) ((g) ^ (((g) >> 2) & 7))

// ---------------------------------------------------------------------------
// Threefry-2x32-20 (JAX), key = (0, 42)  [verified bit-exact in round 2]
// ---------------------------------------------------------------------------
__device__ __forceinline__ uint32_t rotl32(uint32_t x, int r) {
  return (x << r) | (x >> (32 - r));
}

__device__ __forceinline__ void threefry2x32(uint32_t x0, uint32_t x1,
                                             uint32_t& o0, uint32_t& o1) {
  const uint32_t k0 = 0u, k1 = 42u;
  const uint32_t k2 = k0 ^ k1 ^ 0x1BD11BDAu;
  x0 += k0; x1 += k1;
#define TF_ROUND(r) { x0 += x1; x1 = rotl32(x1, (r)); x1 ^= x0; }
  TF_ROUND(13) TF_ROUND(15) TF_ROUND(26) TF_ROUND(6)
  x0 += k1; x1 += k2 + 1u;
  TF_ROUND(17) TF_ROUND(29) TF_ROUND(16) TF_ROUND(24)
  x0 += k2; x1 += k0 + 2u;
  TF_ROUND(13) TF_ROUND(15) TF_ROUND(26) TF_ROUND(6)
  x0 += k0; x1 += k1 + 3u;
  TF_ROUND(17) TF_ROUND(29) TF_ROUND(16) TF_ROUND(24)
  x0 += k1; x1 += k2 + 4u;
  TF_ROUND(13) TF_ROUND(15) TF_ROUND(26) TF_ROUND(6)
  x0 += k2; x1 += k0 + 5u;
#undef TF_ROUND
  o0 = x0; o1 = x1;
}

__device__ __forceinline__ float gumbel_at(uint32_t i) {
  uint32_t o0, o1;
  threefry2x32(0u, i, o0, o1);
  uint32_t bits = o0 ^ o1;
  float f = __uint_as_float((bits >> 9) | 0x3F800000u) - 1.0f;  // [0,1)
  float u = fmaxf(1e-20f, f + 1e-20f);
  return -logf(-logf(u));
}

// monotonic float->uint mapping (IEEE total order for finite values)
__device__ __forceinline__ uint32_t fmono(float v) {
  uint32_t b = __float_as_uint(v);
  return (b & 0x80000000u) ? ~b : (b | 0x80000000u);
}

__device__ __forceinline__ unsigned short f2bf(float x) {
  __hip_bfloat16 h = __float2bfloat16(x);
  return *reinterpret_cast<unsigned short*>(&h);
}

__device__ __forceinline__ float bfu2f(unsigned short v) {
  __hip_bfloat16 h = *reinterpret_cast<__hip_bfloat16*>(&v);
  return __bfloat162float(h);
}

__device__ __forceinline__ unsigned short f2h(float x) {
  __half h = __float2half(x);
  return *reinterpret_cast<unsigned short*>(&h);
}

// 2-limb f16 split with scaled residual: x ~= s0 + s1/2048, err ~2^-22|x|.
// s0 forced to 0 when f16(x) would be subnormal -> denormal-mode-robust.
__device__ __forceinline__ void split2h(float x, short& s0, short& s1) {
  float f0 = 0.0f;
  unsigned short u0 = 0;
  if (fabsf(x) >= 6.2e-5f) {
    __half h0 = __float2half(x);
    f0 = __half2float(h0);
    u0 = *reinterpret_cast<unsigned short*>(&h0);
  }
  __half h1 = __float2half((x - f0) * 2048.0f);
  s0 = (short)u0;
  s1 = *reinterpret_cast<short*>(&h1);
}

// ---------------------------------------------------------------------------
// f32 SIMT GEMM (conflict-free 4+4 split tile). Used only for L1 (K=32).
// OUTMODE 2: relu+split2h -> k-tiled planes [2][N/32][M][32].
// ---------------------------------------------------------------------------
template<int BM, int BN, int BK, int THREADS, bool RELU, bool BT, bool HASBIAS,
         int OUTMODE>
__global__ __launch_bounds__(THREADS) void gemm_kernel(
    const float* __restrict__ A, const float* __restrict__ W,
    const float* __restrict__ bias, float* __restrict__ C,
    int M, int N, int K, short* __restrict__ osplit, int pitchM)
{
  __shared__ __align__(16) float As[BK][BM + 4];
  __shared__ __align__(16) float Ws[BK][BN + 4];
  constexpr int TX = BN / 8;
  constexpr int TY = BM / 8;
  static_assert(TX * TY == THREADS, "bad tiling");
  constexpr int KV = BK / 4;

  const int tid = threadIdx.x;
  const int tx = tid % TX, ty = tid / TX;
  const int row0 = blockIdx.x * BM, col0 = blockIdx.y * BN;

  float acc[8][8];
#pragma unroll
  for (int i = 0; i < 8; ++i)
#pragma unroll
    for (int j = 0; j < 8; ++j) acc[i][j] = 0.0f;

  for (int k0 = 0; k0 < K; k0 += BK) {
#pragma unroll
    for (int e = tid; e < BM * KV; e += THREADS) {
      int m = e / KV, kq = e % KV;
      float4 v = *reinterpret_cast<const float4*>(
          &A[(size_t)(row0 + m) * K + k0 + kq * 4]);
      As[kq * 4 + 0][m] = v.x; As[kq * 4 + 1][m] = v.y;
      As[kq * 4 + 2][m] = v.z; As[kq * 4 + 3][m] = v.w;
    }
    if (BT) {
#pragma unroll
      for (int e = tid; e < BN * KV; e += THREADS) {
        int c = e / KV, kq = e % KV;
        float4 v = *reinterpret_cast<const float4*>(
            &W[(size_t)(col0 + c) * K + k0 + kq * 4]);
        Ws[kq * 4 + 0][c] = v.x; Ws[kq * 4 + 1][c] = v.y;
        Ws[kq * 4 + 2][c] = v.z; Ws[kq * 4 + 3][c] = v.w;
      }
    } else {
      constexpr int CV = BN / 4;
#pragma unroll
      for (int e = tid; e < BK * CV; e += THREADS) {
        int kk = e / CV, c4 = e % CV;
        float4 v = *reinterpret_cast<const float4*>(
            &W[(size_t)(k0 + kk) * N + col0 + c4 * 4]);
        *reinterpret_cast<float4*>(&Ws[kk][c4 * 4]) = v;
      }
    }
    __syncthreads();

#pragma unroll
    for (int kk = 0; kk < BK; ++kk) {
      float a[2][4], w[2][4];
      *reinterpret_cast<float4*>(a[0]) =
          *reinterpret_cast<const float4*>(&As[kk][ty * 4]);
      *reinterpret_cast<float4*>(a[1]) =
          *reinterpret_cast<const float4*>(&As[kk][BM / 2 + ty * 4]);
      *reinterpret_cast<float4*>(w[0]) =
          *reinterpret_cast<const float4*>(&Ws[kk][tx * 4]);
      *reinterpret_cast<float4*>(w[1]) =
          *reinterpret_cast<const float4*>(&Ws[kk][BN / 2 + tx * 4]);
#pragma unroll
      for (int ih = 0; ih < 2; ++ih)
#pragma unroll
        for (int i = 0; i < 4; ++i)
#pragma unroll
          for (int jh = 0; jh < 2; ++jh)
#pragma unroll
            for (int j = 0; j < 4; ++j)
              acc[ih * 4 + i][jh * 4 + j] =
                  fmaf(a[ih][i], w[jh][j], acc[ih * 4 + i][jh * 4 + j]);
    }
    __syncthreads();
  }

#pragma unroll
  for (int ih = 0; ih < 2; ++ih)
#pragma unroll
    for (int i = 0; i < 4; ++i) {
      const int rr = row0 + ih * (BM / 2) + ty * 4 + i;
#pragma unroll
      for (int jh = 0; jh < 2; ++jh) {
        int c = col0 + jh * (BN / 2) + tx * 4;
        float4 v = make_float4(acc[ih * 4 + i][jh * 4 + 0],
                               acc[ih * 4 + i][jh * 4 + 1],
                               acc[ih * 4 + i][jh * 4 + 2],
                               acc[ih * 4 + i][jh * 4 + 3]);
        if (HASBIAS) {
          v.x += bias[c + 0]; v.y += bias[c + 1];
          v.z += bias[c + 2]; v.w += bias[c + 3];
        }
        if (RELU) {
          v.x = fmaxf(v.x, 0.f); v.y = fmaxf(v.y, 0.f);
          v.z = fmaxf(v.z, 0.f); v.w = fmaxf(v.w, 0.f);
        }
        if (OUTMODE == 2) {
          float vv[4] = {v.x, v.y, v.z, v.w};
          size_t ps = (size_t)pitchM * N;
#pragma unroll
          for (int j = 0; j < 4; ++j) {
            short s0, s1; split2h(vv[j], s0, s1);
            int cc = c + j;
            size_t o = ((size_t)(cc >> 5) * pitchM + rr) * 32 + (cc & 31);
            osplit[o] = s0; osplit[o + ps] = s1;
          }
        } else {
          *reinterpret_cast<float4*>(&C[(size_t)rr * N + c]) = v;
        }
      }
    }
}

// ---------------------------------------------------------------------------
// W2 (256x512) + W3 (512x768) -> 2-limb f16 k-tiled planes, one kernel.
// ---------------------------------------------------------------------------
__global__ __launch_bounds__(256) void presplit_w2x2(
    const float* __restrict__ A, const float* __restrict__ B,
    short* __restrict__ oA, short* __restrict__ oB)
{
  const int tA = 256 * 512, tB = 512 * 768;
  for (int idx = blockIdx.x * 256 + threadIdx.x; idx < tA + tB;
       idx += gridDim.x * 256) {
    if (idx < tA) {
      int k = idx / 512, n = idx - k * 512;
      short s0, s1; split2h(A[idx], s0, s1);
      size_t o = ((size_t)(k >> 5) * 512 + n) * 32 + (k & 31);
      oA[o] = s0; oA[o + tA] = s1;
    } else {
      int e = idx - tA;
      int k = e / 768, n = e - k * 768;
      short s0, s1; split2h(B[e], s0, s1);
      size_t o = ((size_t)(k >> 5) * 768 + n) * 32 + (k & 31);
      oB[o] = s0; oB[o + tB] = s1;
    }
  }
}

// legacy single-matrix 2-limb presplit (Path B)
__global__ __launch_bounds__(256) void presplit_w2(
    const float* __restrict__ W, short* __restrict__ out, int K, int N)
{
  const int total = K * N;
  const size_t ps = (size_t)K * N;
  for (int idx = blockIdx.x * 256 + threadIdx.x; idx < total;
       idx += gridDim.x * 256) {
    int k = idx / N, n = idx - k * N;
    short s0, s1; split2h(W[idx], s0, s1);
    size_t o = ((size_t)(k >> 5) * N + n) * 32 + (k & 31);
    out[o] = s0; out[o + ps] = s1;
  }
}

// three 768x768 matrices -> 1-plane f16 k-tiled (value-only path weights)
__global__ __launch_bounds__(256) void presplit_w1x3(
    const float* __restrict__ A, const float* __restrict__ B,
    const float* __restrict__ C,
    short* __restrict__ oA, short* __restrict__ oB, short* __restrict__ oC)
{
  const int total = 768 * 768;
  for (int idx = blockIdx.x * 256 + threadIdx.x; idx < 3 * total;
       idx += gridDim.x * 256) {
    int seg = idx / total, e = idx - seg * total;
    const float* src = (seg == 0) ? A : ((seg == 1) ? B : C);
    short* dst = (seg == 0) ? oA : ((seg == 1) ? oB : oC);
    int k = e / 768, n = e - k * 768;
    size_t o = ((size_t)(k >> 5) * 768 + n) * 32 + (k & 31);
    dst[o] = (short)f2h(src[e]);
  }
}

// ---------------------------------------------------------------------------
// Fold scores weights through W4 (fused 2-limb f16 split) + bias2.
// grid 769: blocks 0..767 -> Ws2 rows; block 768 -> bias2.
// ---------------------------------------------------------------------------
__global__ __launch_bounds__(128) void fold_ws2(
    const float* __restrict__ W4, const float* __restrict__ selw,
    short* __restrict__ Ws2s, const float* __restrict__ b4,
    float* __restrict__ bias2)
{
  const int i = blockIdx.x;
  const int k = threadIdx.x;
  if (i == 768) {
    float s = 0.0f;
    for (int d = 0; d < 768; ++d)
      s = fmaf(b4[d], selw[(size_t)k * 768 + d], s);
    bias2[k] = s;
    return;
  }
  __shared__ float w4row[768];
  for (int j = k; j < 768; j += 128) w4row[j] = W4[(size_t)i * 768 + j];
  __syncthreads();
  float acc = 0.0f;
  const float* sr = selw + (size_t)k * 768;
#pragma unroll 8
  for (int j = 0; j < 768; ++j) acc = fmaf(w4row[j], sr[j], acc);
  short s0, s1; split2h(acc, s0, s1);
  const size_t ps = (size_t)768 * 128;
  size_t o = ((size_t)(i >> 5) * 128 + k) * 32 + (i & 31);
  Ws2s[o] = s0; Ws2s[o + ps] = s1;
}

// ---------------------------------------------------------------------------
// MFMA GEMM, plane-input only.
// LIMBS=2: f16 2-limb scaled-residual, 3 MFMAs/ktile, dual accumulator.
// LIMBS=1: plain f16 (plane 0), 1 MFMA/ktile (value-only path).
// A planes [LIMBS][kfull/32][apitch][32]; optional rowmap gather.
// MODE 0: relu(+bias) -> split2h planes, pitch opitch, row offset r0
// MODE 1: (+bias if nonnull, opt RELUF) -> f32 rows [M][N]
// MODE 2: Path B combo (pf bf16 / scores f32 via W2g)
// MODE 4: (+bias) -> bf16 rows [M][N]
// MODE 5: relu(+bias) -> 1-plane f16 k-tiled, pitch opitch
// MODE 7: relu(+bias) -> split2h planes (pitch opitch, local row) AND
//         limb0 -> persistent 1-plane f16, global pitch 65536, offset r0.
// MODE 8: scores-direct: out row=k(0..127), col=local m; writes
//         sgT[(gm>>13)<<20 | k<<13 | (gm&8191)] = x + bias[k] + gumbel(idx),
//         gm = r0 + col. (fout = sgT)
// ---------------------------------------------------------------------------
template<int MODE, int LIMBS, bool RELUF>
__global__ __launch_bounds__(256) void mfma_gemm(
    const void* __restrict__ Agv, const short* __restrict__ Wg,
    const short* __restrict__ W2g,
    const float* __restrict__ bias, const float* __restrict__ bias2,
    short* __restrict__ out_split, unsigned short* __restrict__ pfout,
    float* __restrict__ fout, int M, int N, int K, int r0,
    const int* __restrict__ rowmap,
    int kbase, int kfull, int apitch, int opitch)
{
  __shared__ __align__(16) short Als[LIMBS][128 * 32];
  __shared__ __align__(16) short Bls[LIMBS][128 * 32];

  const int tid = threadIdx.x;
  const int lane = tid & 63;
  const int wid = tid >> 6;
  const int wm = wid >> 1, wn = wid & 1;
  const int fr = lane & 15, kg = lane >> 4;
  const int row0 = blockIdx.x * 128;
  const bool SC = (MODE == 2) && ((int)blockIdx.y == (int)gridDim.y - 1);
  const short* Wsrc = SC ? W2g : Wg;
  const int Nw = SC ? 128 : N;
  const int col0 = SC ? 0 : blockIdx.y * 128;
  const short* Ag = (const short*)Agv;
  const size_t planeA = (size_t)apitch * kfull;
  const size_t planeW = (size_t)Nw * kfull;
  const int kb = kbase >> 5;

  const int su0 = tid, su1 = tid + 256;
  int ar0 = row0 + (su0 >> 2), ar1 = row0 + (su1 >> 2);
  if (rowmap) { ar0 = rowmap[ar0]; ar1 = rowmap[ar1]; }
  const int br0 = col0 + (su0 >> 2), br1 = col0 + (su1 >> 2);
  const int acol0 = (su0 & 3) * 8, acol1 = (su1 & 3) * 8;
  const int sb0 = SWZG(su0) * 8, sb1 = SWZG(su1) * 8;  // swizzled LDS bases

  f32x4 acc0[4][4];
  f32x4 accX[4][4];
#pragma unroll
  for (int i = 0; i < 4; ++i)
#pragma unroll
    for (int j = 0; j < 4; ++j) { acc0[i][j] = (f32x4)0.0f; accX[i][j] = (f32x4)0.0f; }

  const int nk = K >> 5;
  bf16x8 stA[LIMBS][2], stB[LIMBS][2];

  // initial prefetch (kt = 0)
#pragma unroll
  for (int s = 0; s < LIMBS; ++s) {
    const short* pa = Ag + (size_t)s * planeA + (size_t)kb * apitch * 32;
    const short* pb = Wsrc + (size_t)s * planeW + (size_t)kb * Nw * 32;
    stA[s][0] = *(const bf16x8*)(pa + (size_t)ar0 * 32 + acol0);
    stA[s][1] = *(const bf16x8*)(pa + (size_t)ar1 * 32 + acol1);
    stB[s][0] = *(const bf16x8*)(pb + (size_t)br0 * 32 + acol0);
    stB[s][1] = *(const bf16x8*)(pb + (size_t)br1 * 32 + acol1);
  }

  for (int kt = 0; kt < nk; ++kt) {
    __syncthreads();  // previous tile reads complete
    // --- write LDS (swizzled) ---
#pragma unroll
    for (int s = 0; s < LIMBS; ++s) {
      *(bf16x8*)(&Als[s][sb0]) = stA[s][0];
      *(bf16x8*)(&Als[s][sb1]) = stA[s][1];
      *(bf16x8*)(&Bls[s][sb0]) = stB[s][0];
      *(bf16x8*)(&Bls[s][sb1]) = stB[s][1];
    }
    // --- prefetch next tile ---
    if (kt + 1 < nk) {
#pragma unroll
      for (int s = 0; s < LIMBS; ++s) {
        const short* pa = Ag + (size_t)s * planeA +
                          (size_t)(kb + kt + 1) * apitch * 32;
        const short* pb = Wsrc + (size_t)s * planeW +
                          (size_t)(kb + kt + 1) * Nw * 32;
        stA[s][0] = *(const bf16x8*)(pa + (size_t)ar0 * 32 + acol0);
        stA[s][1] = *(const bf16x8*)(pa + (size_t)ar1 * 32 + acol1);
        stB[s][0] = *(const bf16x8*)(pb + (size_t)br0 * 32 + acol0);
        stB[s][1] = *(const bf16x8*)(pb + (size_t)br1 * 32 + acol1);
      }
    }
    __syncthreads();  // LDS writes visible

    if (LIMBS == 2) {
      f16x8 a0[4], b0[4];
#pragma unroll
      for (int t = 0; t < 4; ++t) {
        const int ga = ((wm * 64 + t * 16 + fr) << 2) | kg;
        const int gb = ((wn * 64 + t * 16 + fr) << 2) | kg;
        a0[t] = *(const f16x8*)(&Als[0][SWZG(ga) * 8]);
        b0[t] = *(const f16x8*)(&Bls[0][SWZG(gb) * 8]);
      }
#pragma unroll
      for (int mt = 0; mt < 4; ++mt)
#pragma unroll
        for (int nt = 0; nt < 4; ++nt)
          acc0[mt][nt] = __builtin_amdgcn_mfma_f32_16x16x32_f16(
              a0[mt], b0[nt], acc0[mt][nt], 0, 0, 0);
      f16x8 x1[4];
#pragma unroll
      for (int t = 0; t < 4; ++t) {
        const int gb = ((wn * 64 + t * 16 + fr) << 2) | kg;
        x1[t] = *(const f16x8*)(&Bls[LIMBS - 1][SWZG(gb) * 8]);
      }
#pragma unroll
      for (int mt = 0; mt < 4; ++mt)
#pragma unroll
        for (int nt = 0; nt < 4; ++nt)
          accX[mt][nt] = __builtin_amdgcn_mfma_f32_16x16x32_f16(
              a0[mt], x1[nt], accX[mt][nt], 0, 0, 0);
#pragma unroll
      for (int t = 0; t < 4; ++t) {
        const int ga = ((wm * 64 + t * 16 + fr) << 2) | kg;
        x1[t] = *(const f16x8*)(&Als[LIMBS - 1][SWZG(ga) * 8]);
      }
#pragma unroll
      for (int mt = 0; mt < 4; ++mt)
#pragma unroll
        for (int nt = 0; nt < 4; ++nt)
          accX[mt][nt] = __builtin_amdgcn_mfma_f32_16x16x32_f16(
              x1[mt], b0[nt], accX[mt][nt], 0, 0, 0);
    } else {
      f16x8 a0[4], b0[4];
#pragma unroll
      for (int t = 0; t < 4; ++t) {
        const int ga = ((wm * 64 + t * 16 + fr) << 2) | kg;
        const int gb = ((wn * 64 + t * 16 + fr) << 2) | kg;
        a0[t] = *(const f16x8*)(&Als[0][SWZG(ga) * 8]);
        b0[t] = *(const f16x8*)(&Bls[0][SWZG(gb) * 8]);
      }
#pragma unroll
      for (int mt = 0; mt < 4; ++mt)
#pragma unroll
        for (int nt = 0; nt < 4; ++nt)
          acc0[mt][nt] = __builtin_amdgcn_mfma_f32_16x16x32_f16(
              a0[mt], b0[nt], acc0[mt][nt], 0, 0, 0);
    }
  }

  // epilogue: C frag mapping col = lane&15, row = (lane>>4)*4 + r  [m89]
  const size_t psO = (size_t)opitch * N;
#pragma unroll
  for (int mt = 0; mt < 4; ++mt)
#pragma unroll
    for (int nt = 0; nt < 4; ++nt)
#pragma unroll
      for (int r = 0; r < 4; ++r) {
        int row = row0 + wm * 64 + mt * 16 + kg * 4 + r;
        int col = col0 + wn * 64 + nt * 16 + fr;
        float x = acc0[mt][nt][r];
        if (LIMBS == 2) x += accX[mt][nt][r] * 4.8828125e-4f;  // 2^-11
        if (MODE == 2) {
          if (SC) {
            fout[(size_t)row * 128 + col] = x + bias2[col];
          } else {
            pfout[(size_t)(r0 + row) * 768 + col] = f2bf(x + bias[col]);
          }
        } else if (MODE == 1) {
          if (bias) x += bias[col];
          if (RELUF) x = fmaxf(x, 0.0f);
          fout[(size_t)row * N + col] = x;
        } else if (MODE == 4) {
          pfout[(size_t)row * N + col] = f2bf(x + bias[col]);
        } else if (MODE == 5) {
          x = fmaxf(x + bias[col], 0.0f);
          size_t o = ((size_t)(col >> 5) * opitch + row) * 32 + (col & 31);
          out_split[o] = (short)f2h(x);
        } else if (MODE == 7) {
          x = fmaxf(x + bias[col], 0.0f);
          short s0, s1; split2h(x, s0, s1);
          size_t o = ((size_t)(col >> 5) * opitch + row) * 32 + (col & 31);
          out_split[o] = s0; out_split[o + psO] = s1;
          size_t op = ((size_t)(col >> 5) * 65536 + (r0 + row)) * 32 + (col & 31);
          ((short*)pfout)[op] = s0;
        } else if (MODE == 8) {
          x += bias[row];                      // bias2 indexed by k = row
          const int gm = r0 + col;
          const uint32_t idx = ((uint32_t)(gm >> 13) << 20) |
                               ((uint32_t)row << 13) | (uint32_t)(gm & 8191);
          fout[idx] = x + gumbel_at(idx);
        } else {  // MODE 0
          x = fmaxf(x + bias[col], 0.0f);
          short s0, s1; split2h(x, s0, s1);
          size_t o = ((size_t)(col >> 5) * opitch + (r0 + row)) * 32 + (col & 31);
          out_split[o] = s0; out_split[o + psO] = s1;
        }
      }
}

// ---------------------------------------------------------------------------
// Path B: scores [rows][128] f32 -> sgT[b][k][m] with fused Gumbel noise.
// ---------------------------------------------------------------------------
__global__ __launch_bounds__(256) void gumbel_transpose(
    const float* __restrict__ sc, float* __restrict__ sgT, int r0)
{
  __shared__ float tile[32][33];
  const int lm0 = blockIdx.x * 32;
  const int k0 = blockIdx.y * 32;
  const int tx = threadIdx.x, ty = threadIdx.y;
#pragma unroll
  for (int rr = ty; rr < 32; rr += 8)
    tile[rr][tx] = sc[(size_t)(lm0 + rr) * 128 + k0 + tx];
  __syncthreads();
#pragma unroll
  for (int rr = ty; rr < 32; rr += 8) {
    int k = k0 + rr;
    int gm = r0 + lm0 + tx;
    uint32_t idx = ((uint32_t)(gm >> 13) << 20) | ((uint32_t)k << 13) |
                   (uint32_t)(gm & 8191);
    sgT[idx] = tile[tx][rr] + gumbel_at(idx);
  }
}

// ---------------------------------------------------------------------------
// Per-(b,k) top-32 of sgT row — register-resident incremental tournament.
// ---------------------------------------------------------------------------
__global__ __launch_bounds__(256) void top_candidates(
    const float* __restrict__ sgT, u64* __restrict__ cand)
{
  const int q = blockIdx.x;
  const int tid = threadIdx.x;
  const int lane = tid & 63, wid = tid >> 6;
  __shared__ u64 wb[4];
  u64 pr[32];
  const float4* row4 = reinterpret_cast<const float4*>(sgT + (size_t)q * 8192);
#pragma unroll
  for (int j = 0; j < 8; ++j) {
    float4 v = row4[tid + j * 256];
    const int mb = (tid + j * 256) * 4;
    pr[j * 4 + 0] = ((u64)fmono(v.x) << 13) | (u64)(8191 - (mb + 0));
    pr[j * 4 + 1] = ((u64)fmono(v.y) << 13) | (u64)(8191 - (mb + 1));
    pr[j * 4 + 2] = ((u64)fmono(v.z) << 13) | (u64)(8191 - (mb + 2));
    pr[j * 4 + 3] = ((u64)fmono(v.w) << 13) | (u64)(8191 - (mb + 3));
  }
  u64 lmax = 0;
#pragma unroll
  for (int r = 0; r < 32; ++r) if (pr[r] > lmax) lmax = pr[r];

  for (int it = 0; it < 32; ++it) {
    u64 loc = lmax;
#pragma unroll
    for (int off = 32; off; off >>= 1) {
      u64 o = __shfl_down(loc, off);
      if (o > loc) loc = o;
    }
    if (lane == 0) wb[wid] = loc;
    __syncthreads();
    u64 w01 = (wb[0] > wb[1]) ? wb[0] : wb[1];
    u64 w23 = (wb[2] > wb[3]) ? wb[2] : wb[3];
    u64 winner = (w01 > w23) ? w01 : w23;
    __syncthreads();
    if (tid == 0) cand[(size_t)q * 32 + it] = winner;
    const int wmm = 8191 - (int)(winner & 0x1FFFull);
    if (((wmm >> 2) & 255) == tid) {
      const int orr = ((wmm >> 10) << 2) | (wmm & 3);
#pragma unroll
      for (int r = 0; r < 32; ++r) if (r == orr) pr[r] = 0;
      lmax = 0;
#pragma unroll
      for (int r = 0; r < 32; ++r) if (pr[r] > lmax) lmax = pr[r];
    }
  }
}

// ---------------------------------------------------------------------------
// Sequential resolve from LDS-resident candidate lists. grid (8), block 64.
// ---------------------------------------------------------------------------
__global__ __launch_bounds__(64) void resolve_kernel(
    const u64* __restrict__ cand, const float* __restrict__ sgT,
    int* __restrict__ sel)
{
  const int b = blockIdx.x;
  const int lane = threadIdx.x;
  __shared__ u64 candL[4096];
  __shared__ uint32_t avail[256];
  for (int j = lane; j < 4096; j += 64) candL[j] = cand[(size_t)b * 4096 + j];
#pragma unroll
  for (int j = lane; j < 256; j += 64) avail[j] = 0xFFFFFFFFu;
  __syncthreads();

  for (int k = 0; k < 128; ++k) {
    u64 c = (lane < 32) ? candL[k * 32 + lane] : 0ull;
    int m = 8191 - (int)(c & 0x1FFFull);
    bool av = (lane < 32) && ((avail[m >> 5] >> (m & 31)) & 1u);
    u64 bal = __ballot(av);
    int pick;
    if (bal) {
      int j = __builtin_ctzll(bal);
      pick = __shfl(m, j);
    } else {
      u64 best = 0ull;
      const float* row = sgT + (size_t)(b * 128 + k) * 8192;
      for (int mm = lane; mm < 8192; mm += 64) {
        if ((avail[mm >> 5] >> (mm & 31)) & 1u) {
          u64 p = ((u64)fmono(row[mm]) << 13) | (u64)(8191 - mm);
          if (p > best) best = p;
        }
      }
#pragma unroll
      for (int off = 32; off; off >>= 1) {
        u64 o = __shfl_down(best, off);
        if (o > best) best = o;
      }
      best = __shfl(best, 0);
      pick = 8191 - (int)(best & 0x1FFFull);
    }
    if (lane == 0) {
      sel[b * 128 + k] = pick;
      avail[pick >> 5] &= ~(1u << (pick & 31));
    }
    __syncthreads();
  }
}

// ---------------------------------------------------------------------------
// KNN: d2 to 8192 points (LDS), 16 argmin passes.
// POOL=true: fused max-pool from full pf (bf16), split2h planes out (Path B).
// POOL=false: write rowlist directly (Path A):
//   rowlist[q] = global selected row; rowlist[1024 + q*16 + it] = nbr rows.
// ---------------------------------------------------------------------------
template<bool POOL>
__global__ __launch_bounds__(256) void knn_kernel(
    const float* __restrict__ coords,
    const __hip_bfloat16* __restrict__ pf,
    const int* __restrict__ sel_idx,
    short* __restrict__ pooled_s,
    int* __restrict__ rowlist_g)
{
  const int q = blockIdx.x;
  const int b = q >> 7;
  const int tid = threadIdx.x;
  const int lane = tid & 63, wid = tid >> 6;
  __shared__ float d2s[8192];
  __shared__ int nbrs[16];
  __shared__ u64 wb[4];

  const int sidx = sel_idx[q];
  const float* cbase = coords + (size_t)b * 8192 * 5;
  const float cx = cbase[sidx * 5 + 1];
  const float cy = cbase[sidx * 5 + 2];
  const float cz = cbase[sidx * 5 + 3];
  const float ss = cx * cx + cy * cy + cz * cz;

  for (int j = 0; j < 32; ++j) {
    int m = tid + j * 256;
    float px = cbase[m * 5 + 1], py = cbase[m * 5 + 2], pz = cbase[m * 5 + 3];
    d2s[m] = ss + (px * px + py * py + pz * pz)
               - 2.0f * (cx * px + cy * py + cz * pz);
  }
  __syncthreads();

  for (int it = 0; it < 16; ++it) {
    u64 loc = ~0ull;
    for (int j = 0; j < 32; ++j) {
      int m = tid + j * 256;
      u64 p = ((u64)fmono(d2s[m]) << 13) | (u64)m;
      if (p < loc) loc = p;
    }
#pragma unroll
    for (int off = 32; off; off >>= 1) {
      u64 o = __shfl_down(loc, off);
      if (o < loc) loc = o;
    }
    if (lane == 0) wb[wid] = loc;
    __syncthreads();
    if (tid == 0) {
      u64 best = wb[0];
      if (wb[1] < best) best = wb[1];
      if (wb[2] < best) best = wb[2];
      if (wb[3] < best) best = wb[3];
      int m = (int)(best & 0x1FFFull);
      nbrs[it] = m;
      d2s[m] = __uint_as_float(0x7F800000u);
    }
    __syncthreads();
  }

  if (POOL) {
    const size_t ps = (size_t)1024 * 768;
    for (int d = tid; d < 768; d += 256) {
      float mx = -__uint_as_float(0x7F800000u);
#pragma unroll
      for (int it = 0; it < 16; ++it) {
        float v = __bfloat162float(pf[((size_t)b * 8192 + nbrs[it]) * 768 + d]);
        mx = fmaxf(mx, v);
      }
      short s0, s1; split2h(mx, s0, s1);
      size_t o = ((size_t)(d >> 5) * 1024 + q) * 32 + (d & 31);
      pooled_s[o] = s0; pooled_s[o + ps] = s1;
    }
  } else {
    if (tid < 16) rowlist_g[1024 + q * 16 + tid] = b * 8192 + nbrs[tid];
    if (tid == 16) rowlist_g[q] = b * 8192 + sidx;
  }
}

// pooled (1-plane f16 k-tiled) from pf_sub neighbor rows. grid (1024).
__global__ __launch_bounds__(256) void pool_from_sub(
    const unsigned short* __restrict__ pf_sub, short* __restrict__ pooled_s)
{
  const int q = blockIdx.x;
  const int tid = threadIdx.x;
  const unsigned short* base = pf_sub + (size_t)(1024 + q * 16) * 768;
  for (int d = tid; d < 768; d += 256) {
    float mx = -__uint_as_float(0x7F800000u);
#pragma unroll
    for (int it = 0; it < 16; ++it)
      mx = fmaxf(mx, bfu2f(base[(size_t)it * 768 + d]));
    size_t o = ((size_t)(d >> 5) * 1024 + q) * 32 + (d & 31);
    pooled_s[o] = (short)f2h(mx);
  }
}

// ---------------------------------------------------------------------------
// Parallel finalize.
// ---------------------------------------------------------------------------
__global__ __launch_bounds__(128) void rank_cent(
    const float* __restrict__ coords, const int* __restrict__ sel_idx,
    int* __restrict__ rank_g, float* __restrict__ out)
{
  const int b = blockIdx.x;
  const int tid = threadIdx.x;
  __shared__ float tvals[128];
  const float* cbase = coords + (size_t)b * 8192 * 5;
  const int q = (b << 7) + tid;
  const int sidx = sel_idx[q];
  tvals[tid] = cbase[sidx * 5 + 4];
  __syncthreads();
  float t = tvals[tid];
  int r = 0;
#pragma unroll 8
  for (int j = 0; j < 128; ++j) {
    float tj = tvals[j];
    r += (tj < t || (tj == t && j < tid)) ? 1 : 0;
  }
  rank_g[q] = r;
  float* cent = out + 786432;
  float* mask = out + 786432 + 4096;
  cent[((b << 7) + r) * 4 + 0] = cbase[sidx * 5 + 1];
  cent[((b << 7) + r) * 4 + 1] = cbase[sidx * 5 + 2];
  cent[((b << 7) + r) * 4 + 2] = cbase[sidx * 5 + 3];
  cent[((b << 7) + r) * 4 + 3] = cbase[sidx * 5 + 4];
  mask[q] = 1.0f;
}

__global__ __launch_bounds__(192) void token_write(
    const unsigned short* __restrict__ feat, const float* __restrict__ agg,
    const int* __restrict__ rank_g, const int* __restrict__ selmap,
    float* __restrict__ out)
{
  const int b = blockIdx.x, i = blockIdx.y;
  const int q = (b << 7) + i;
  const int tid = threadIdx.x;
  const int r = rank_g[q];
  const unsigned short* src =
      selmap ? feat + ((size_t)b * 8192 + selmap[q]) * 768
             : feat + (size_t)q * 768;
  const float* asrc = agg + (size_t)q * 768;
  float* dst = out + ((size_t)(b << 7) + r) * 768;
  for (int d = tid; d < 768; d += 192)
    dst[d] = bfu2f(src[d]) + asrc[d];
}

// ---------------------------------------------------------------------------
// host launcher — Path A'' (deferred pf, sgT unioned, Mc=16384, scores
// direct-to-sgT) when ws allows, else Path B.
// ---------------------------------------------------------------------------
extern "C" void kernel_launch(void* const* d_in, const int* in_sizes, int n_in,
                              void* d_out, int out_size, void* d_ws, size_t ws_size,
                              hipStream_t stream) {
  const float* coords = (const float*)d_in[0];
  const float* feats  = (const float*)d_in[1];
  const float* W1 = (const float*)d_in[2];  const float* b1 = (const float*)d_in[3];
  const float* W2 = (const float*)d_in[4];  const float* b2 = (const float*)d_in[5];
  const float* W3 = (const float*)d_in[6];  const float* b3 = (const float*)d_in[7];
  const float* W4 = (const float*)d_in[8];  const float* b4 = (const float*)d_in[9];
  const float* selw = (const float*)d_in[10];
  const float* nW1 = (const float*)d_in[11]; const float* nb1 = (const float*)d_in[12];
  const float* nW2 = (const float*)d_in[13]; const float* nb2 = (const float*)d_in[14];
  float* out = (float*)d_out;
  char* ws = (char*)d_ws;
  dim3 blk(256);

  // ---------------- Path A'' layout (persistent ~140.7 MB) ----------------
  size_t a = 0;
  short* h3p0  = (short*)(ws + a);          a += (size_t)65536 * 768 * 2;   // 96MB
  // union region: sgTa (32MiB) OVERLAPS pf_sub+pooled+t1+agg (33.03MB);
  // sgT dead after resolve_kernel, the others written after it.
  const size_t ua = a;
  float* sgTa  = (float*)(ws + ua);
  unsigned short* pf_sub = (unsigned short*)(ws + ua);
  short* pooled_a = (short*)(ws + ua + (size_t)17408 * 768 * 2);
  short* t1sa  = (short*)(ws + ua + (size_t)17408 * 768 * 2 + (size_t)1024 * 768 * 2);
  float* agga  = (float*)(ws + ua + (size_t)17408 * 768 * 2 + (size_t)2 * 1024 * 768 * 2);
  a += (size_t)33554432;                                           // 32 MiB
  short* W2sa  = (short*)(ws + a);          a += (size_t)2 * 256 * 512 * 2;
  short* W3sa  = (short*)(ws + a);          a += (size_t)2 * 512 * 768 * 2;
  short* W4sa  = (short*)(ws + a);          a += (size_t)768 * 768 * 2;
  short* Ws2sa = (short*)(ws + a);          a += (size_t)2 * 768 * 128 * 2;
  short* nW1sa = (short*)(ws + a);          a += (size_t)768 * 768 * 2;
  short* nW2sa = (short*)(ws + a);          a += (size_t)768 * 768 * 2;
  float* bias2a = (float*)(ws + a);         a += 512;
  u64*   canda = (u64*)(ws + a);            a += (size_t)1024 * 32 * 8;
  int*   sela  = (int*)(ws + a);            a += 4096;
  int*   rowlist = (int*)(ws + a);          a += (size_t)17408 * 4;
  int*   rank_a = (int*)(ws + a);           a += 4096;
  a = (a + 255) & ~(size_t)255;
  const size_t tmpA = a;

  // chunk temps (5120 B/row): h2s [0,2048), h1s [2048,3072),
  // h3c [2048,5120) — h3c overlaps h1s (dead after L2).
  int McA = 0;
  {
    const int mc[4] = {16384, 8192, 4096, 2048};
    for (int ci = 0; ci < 4; ++ci)
      if (tmpA + (size_t)5120 * mc[ci] <= ws_size) { McA = mc[ci]; break; }
  }

  if (McA) {
    // =========================== PATH A'' ===========================
    short* h2s = (short*)(ws + tmpA);
    short* h1s = (short*)(ws + tmpA + (size_t)2048 * McA);
    short* h3c = (short*)(ws + tmpA + (size_t)2048 * McA);  // overlaps h1s

    fold_ws2<<<dim3(769), dim3(128), 0, stream>>>(W4, selw, Ws2sa, b4, bias2a);
    presplit_w2x2<<<512, blk, 0, stream>>>(W2, W3, W2sa, W3sa);
    presplit_w1x3<<<512, blk, 0, stream>>>(W4, nW1, nW2, W4sa, nW1sa, nW2sa);

    for (int r0 = 0; r0 < 65536; r0 += McA) {
      const int cm = McA;
      gemm_kernel<128,128,16,256,true ,false,true ,2>
        <<<dim3(cm/128, 2), blk, 0, stream>>>(feats + (size_t)r0 * 32, W1, b1,
                                              nullptr, cm, 256, 32, h1s, cm);
      mfma_gemm<0,2,false><<<dim3(cm/128, 4), blk, 0, stream>>>(
          h1s, W2sa, nullptr, b2, nullptr, h2s, nullptr, nullptr,
          cm, 512, 256, 0, nullptr, 0, 256, cm, cm);
      // L3: chunk 2-limb planes (for scores) + persistent limb0 plane
      mfma_gemm<7,2,false><<<dim3(cm/128, 6), blk, 0, stream>>>(
          h2s, W3sa, nullptr, b3, nullptr, h3c,
          (unsigned short*)h3p0, nullptr,
          cm, 768, 512, r0, nullptr, 0, 512, cm, cm);
      // scores-direct: A=Ws2 (M=128 rows=k), B=h3c (N=cm cols=m);
      // epilogue writes sgT with fused bias2+gumbel.
      mfma_gemm<8,2,false><<<dim3(1, cm/128), blk, 0, stream>>>(
          Ws2sa, h3c, nullptr, bias2a, nullptr, nullptr, nullptr,
          sgTa, 128, cm, 768, r0, nullptr, 0, 768, 128, 0);
    }

    top_candidates<<<dim3(1024), blk, 0, stream>>>(sgTa, canda);
    resolve_kernel<<<dim3(8), dim3(64), 0, stream>>>(canda, sgTa, sela);
    knn_kernel<false><<<dim3(1024), blk, 0, stream>>>(
        coords, nullptr, sela, nullptr, rowlist);
    // gathered L4 from persistent h3 limb0 (f16), 1-limb value path
    mfma_gemm<4,1,false><<<dim3(136, 6), blk, 0, stream>>>(
        h3p0, W4sa, nullptr, b4, nullptr, nullptr, pf_sub, nullptr,
        17408, 768, 768, 0, rowlist, 0, 768, 65536, 0);
    pool_from_sub<<<dim3(1024), blk, 0, stream>>>(pf_sub, pooled_a);
    mfma_gemm<5,1,false><<<dim3(8, 6), blk, 0, stream>>>(
        pooled_a, nW1sa, nullptr, nb1, nullptr, t1sa, nullptr, nullptr,
        1024, 768, 768, 0, nullptr, 0, 768, 1024, 1024);
    mfma_gemm<1,1,false><<<dim3(8, 6), blk, 0, stream>>>(
        t1sa, nW2sa, nullptr, nb2, nullptr, nullptr, nullptr, agga,
        1024, 768, 768, 0, nullptr, 0, 768, 1024, 0);
    rank_cent<<<dim3(8), dim3(128), 0, stream>>>(coords, sela, rank_a, out);
    token_write<<<dim3(8, 128), dim3(192), 0, stream>>>(
        pf_sub, agga, rank_a, nullptr, out);
    return;
  }

  // =========================== PATH B (fallback) ===========================
  size_t off = 0;
  unsigned short* pf = (unsigned short*)(ws + off); off += (size_t)65536 * 768 * 2;
  float* sgT   = (float*)(ws + off);  off += (size_t)8 * 128 * 8192 * 4;
  short* W2s   = (short*)(ws + off);  off += (size_t)2 * 256 * 512 * 2;
  short* W3s   = (short*)(ws + off);  off += (size_t)2 * 512 * 768 * 2;
  short* W4s   = (short*)(ws + off);  off += (size_t)2 * 768 * 768 * 2;
  short* Ws2s  = (short*)(ws + off);  off += (size_t)2 * 768 * 128 * 2;
  short* nW1s  = (short*)(ws + off);  off += (size_t)2 * 768 * 768 * 2;
  short* nW2s  = (short*)(ws + off);  off += (size_t)2 * 768 * 768 * 2;
  float* bias2 = (float*)(ws + off);  off += 512;
  short* pooled_s = (short*)(ws + off); off += (size_t)2 * 1024 * 768 * 2;
  short* t1s   = (short*)(ws + off);  off += (size_t)2 * 1024 * 768 * 2;
  float* agg   = (float*)(ws + off);  off += (size_t)1024 * 768 * 4;
  u64*   cand  = (u64*)(ws + off);    off += (size_t)1024 * 32 * 8;
  int*   sel   = (int*)(ws + off);    off += 4096;
  int*   rank_g = (int*)(ws + off);   off += 4096;
  off = (off + 255) & ~(size_t)255;
  const size_t tmp_off = off;

  int Mc = 512;
  const int mcand[6] = {16384, 8192, 4096, 2048, 1024, 512};
  for (int ci = 0; ci < 6; ++ci) {
    if (tmp_off + (size_t)5120 * mcand[ci] <= ws_size) { Mc = mcand[ci]; break; }
  }
  short* tA = (short*)(ws + tmp_off);                       // h2s (2048 B/row)
  short* tB = (short*)(ws + tmp_off + (size_t)2048 * Mc);   // h1s/h3s (3072 B/row)
  float* scc = (float*)tA;  // alias: h2s dead after L3

  fold_ws2<<<dim3(769), dim3(128), 0, stream>>>(W4, selw, Ws2s, b4, bias2);
  presplit_w2x2<<<512, blk, 0, stream>>>(W2, W3, W2s, W3s);
  presplit_w2<<<256, blk, 0, stream>>>(W4, W4s, 768, 768);
  presplit_w2<<<256, blk, 0, stream>>>(nW1, nW1s, 768, 768);
  presplit_w2<<<256, blk, 0, stream>>>(nW2, nW2s, 768, 768);

  for (int r0 = 0; r0 < 65536; r0 += Mc) {
    const int cm = (65536 - r0 < Mc) ? (65536 - r0) : Mc;
    short* h1s = tB;
    short* h2s = tA;
    short* h3s = tB;  // alias: h1s dead after L2
    gemm_kernel<128,128,16,256,true ,false,true ,2>
      <<<dim3(cm/128, 2), blk, 0, stream>>>(feats + (size_t)r0 * 32, W1, b1,
                                            nullptr, cm, 256, 32, h1s, cm);
    mfma_gemm<0,2,false><<<dim3(cm/128, 4), blk, 0, stream>>>(
        h1s, W2s, nullptr, b2, nullptr, h2s, nullptr, nullptr,
        cm, 512, 256, 0, nullptr, 0, 256, cm, cm);
    mfma_gemm<0,2,false><<<dim3(cm/128, 6), blk, 0, stream>>>(
        h2s, W3s, nullptr, b3, nullptr, h3s, nullptr, nullptr,
        cm, 768, 512, 0, nullptr, 0, 512, cm, cm);
    mfma_gemm<2,2,false><<<dim3(cm/128, 7), blk, 0, stream>>>(
        h3s, W4s, Ws2s, b4, bias2, nullptr, pf, scc,
        cm, 768, 768, r0, nullptr, 0, 768, cm, 0);
    gumbel_transpose<<<dim3(cm/32, 4), dim3(32, 8), 0, stream>>>(scc, sgT, r0);
  }

  top_candidates<<<dim3(1024), blk, 0, stream>>>(sgT, cand);
  resolve_kernel<<<dim3(8), dim3(64), 0, stream>>>(cand, sgT, sel);
  knn_kernel<true ><<<dim3(1024), blk, 0, stream>>>(
      coords, (const __hip_bfloat16*)pf, sel, pooled_s, nullptr);
  mfma_gemm<0,2,false><<<dim3(8, 6), blk, 0, stream>>>(
      pooled_s, nW1s, nullptr, nb1, nullptr, t1s, nullptr, nullptr,
      1024, 768, 768, 0, nullptr, 0, 768, 1024, 1024);
  mfma_gemm<1,2,false><<<dim3(8, 6), blk, 0, stream>>>(
      t1s, nW2s, nullptr, nb2, nullptr, nullptr, nullptr, agg,
      1024, 768, 768, 0, nullptr, 0, 768, 1024, 0);
  rank_cent<<<dim3(8), dim3(128), 0, stream>>>(coords, sel, rank_g, out);
  token_write<<<dim3(8, 128), dim3(192), 0, stream>>>(
      pf, agg, rank_g, sel, out);
}

// Round 16
// 867.143 us; speedup vs baseline: 1.4571x; 1.4233x over previous
//
#include <hip/hip_runtime.h>
#include <hip/hip_bf16.h>
#include <hip/hip_fp16.h>
#include <stdint.h>
#include <stddef.h>

typedef unsigned long long u64;
typedef __attribute__((ext_vector_type(8))) short bf16x8;
typedef __attribute__((ext_vector_type(8))) _Float16 f16x8;
typedef __attribute__((ext_vector_type(4))) float f32x4;

// LDS XOR swizzle in 16B granules (bank-spread for b128 write + frag read)
#define SWZG(g) ((g) ^ (((g) >> 2) & 7))

// ---------------------------------------------------------------------------
// Threefry-2x32-20 (JAX), key = (0, 42)  [verified bit-exact in round 2]
// ---------------------------------------------------------------------------
__device__ __forceinline__ uint32_t rotl32(uint32_t x, int r) {
  return (x << r) | (x >> (32 - r));
}

__device__ __forceinline__ void threefry2x32(uint32_t x0, uint32_t x1,
                                             uint32_t& o0, uint32_t& o1) {
  const uint32_t k0 = 0u, k1 = 42u;
  const uint32_t k2 = k0 ^ k1 ^ 0x1BD11BDAu;
  x0 += k0; x1 += k1;
#define TF_ROUND(r) { x0 += x1; x1 = rotl32(x1, (r)); x1 ^= x0; }
  TF_ROUND(13) TF_ROUND(15) TF_ROUND(26) TF_ROUND(6)
  x0 += k1; x1 += k2 + 1u;
  TF_ROUND(17) TF_ROUND(29) TF_ROUND(16) TF_ROUND(24)
  x0 += k2; x1 += k0 + 2u;
  TF_ROUND(13) TF_ROUND(15) TF_ROUND(26) TF_ROUND(6)
  x0 += k0; x1 += k1 + 3u;
  TF_ROUND(17) TF_ROUND(29) TF_ROUND(16) TF_ROUND(24)
  x0 += k1; x1 += k2 + 4u;
  TF_ROUND(13) TF_ROUND(15) TF_ROUND(26) TF_ROUND(6)
  x0 += k2; x1 += k0 + 5u;
#undef TF_ROUND
  o0 = x0; o1 = x1;
}

__device__ __forceinline__ float gumbel_at(uint32_t i) {
  uint32_t o0, o1;
  threefry2x32(0u, i, o0, o1);
  uint32_t bits = o0 ^ o1;
  float f = __uint_as_float((bits >> 9) | 0x3F800000u) - 1.0f;  // [0,1)
  float u = fmaxf(1e-20f, f + 1e-20f);
  return -logf(-logf(u));
}

// monotonic float->uint mapping (IEEE total order for finite values)
__device__ __forceinline__ uint32_t fmono(float v) {
  uint32_t b = __float_as_uint(v);
  return (b & 0x80000000u) ? ~b : (b | 0x80000000u);
}

__device__ __forceinline__ unsigned short f2bf(float x) {
  __hip_bfloat16 h = __float2bfloat16(x);
  return *reinterpret_cast<unsigned short*>(&h);
}

__device__ __forceinline__ float bfu2f(unsigned short v) {
  __hip_bfloat16 h = *reinterpret_cast<__hip_bfloat16*>(&v);
  return __bfloat162float(h);
}

__device__ __forceinline__ unsigned short f2h(float x) {
  __half h = __float2half(x);
  return *reinterpret_cast<unsigned short*>(&h);
}

// 2-limb f16 split with scaled residual: x ~= s0 + s1/2048, err ~2^-22|x|.
// s0 forced to 0 when f16(x) would be subnormal -> denormal-mode-robust.
__device__ __forceinline__ void split2h(float x, short& s0, short& s1) {
  float f0 = 0.0f;
  unsigned short u0 = 0;
  if (fabsf(x) >= 6.2e-5f) {
    __half h0 = __float2half(x);
    f0 = __half2float(h0);
    u0 = *reinterpret_cast<unsigned short*>(&h0);
  }
  __half h1 = __float2half((x - f0) * 2048.0f);
  s0 = (short)u0;
  s1 = *reinterpret_cast<short*>(&h1);
}

// ---------------------------------------------------------------------------
// f32 SIMT GEMM (conflict-free 4+4 split tile). Used only for L1 (K=32).
// OUTMODE 2: relu+split2h -> k-tiled planes [2][N/32][M][32].
// ---------------------------------------------------------------------------
template<int BM, int BN, int BK, int THREADS, bool RELU, bool BT, bool HASBIAS,
         int OUTMODE>
__global__ __launch_bounds__(THREADS) void gemm_kernel(
    const float* __restrict__ A, const float* __restrict__ W,
    const float* __restrict__ bias, float* __restrict__ C,
    int M, int N, int K, short* __restrict__ osplit, int pitchM)
{
  __shared__ __align__(16) float As[BK][BM + 4];
  __shared__ __align__(16) float Ws[BK][BN + 4];
  constexpr int TX = BN / 8;
  constexpr int TY = BM / 8;
  static_assert(TX * TY == THREADS, "bad tiling");
  constexpr int KV = BK / 4;

  const int tid = threadIdx.x;
  const int tx = tid % TX, ty = tid / TX;
  const int row0 = blockIdx.x * BM, col0 = blockIdx.y * BN;

  float acc[8][8];
#pragma unroll
  for (int i = 0; i < 8; ++i)
#pragma unroll
    for (int j = 0; j < 8; ++j) acc[i][j] = 0.0f;

  for (int k0 = 0; k0 < K; k0 += BK) {
#pragma unroll
    for (int e = tid; e < BM * KV; e += THREADS) {
      int m = e / KV, kq = e % KV;
      float4 v = *reinterpret_cast<const float4*>(
          &A[(size_t)(row0 + m) * K + k0 + kq * 4]);
      As[kq * 4 + 0][m] = v.x; As[kq * 4 + 1][m] = v.y;
      As[kq * 4 + 2][m] = v.z; As[kq * 4 + 3][m] = v.w;
    }
    if (BT) {
#pragma unroll
      for (int e = tid; e < BN * KV; e += THREADS) {
        int c = e / KV, kq = e % KV;
        float4 v = *reinterpret_cast<const float4*>(
            &W[(size_t)(col0 + c) * K + k0 + kq * 4]);
        Ws[kq * 4 + 0][c] = v.x; Ws[kq * 4 + 1][c] = v.y;
        Ws[kq * 4 + 2][c] = v.z; Ws[kq * 4 + 3][c] = v.w;
      }
    } else {
      constexpr int CV = BN / 4;
#pragma unroll
      for (int e = tid; e < BK * CV; e += THREADS) {
        int kk = e / CV, c4 = e % CV;
        float4 v = *reinterpret_cast<const float4*>(
            &W[(size_t)(k0 + kk) * N + col0 + c4 * 4]);
        *reinterpret_cast<float4*>(&Ws[kk][c4 * 4]) = v;
      }
    }
    __syncthreads();

#pragma unroll
    for (int kk = 0; kk < BK; ++kk) {
      float a[2][4], w[2][4];
      *reinterpret_cast<float4*>(a[0]) =
          *reinterpret_cast<const float4*>(&As[kk][ty * 4]);
      *reinterpret_cast<float4*>(a[1]) =
          *reinterpret_cast<const float4*>(&As[kk][BM / 2 + ty * 4]);
      *reinterpret_cast<float4*>(w[0]) =
          *reinterpret_cast<const float4*>(&Ws[kk][tx * 4]);
      *reinterpret_cast<float4*>(w[1]) =
          *reinterpret_cast<const float4*>(&Ws[kk][BN / 2 + tx * 4]);
#pragma unroll
      for (int ih = 0; ih < 2; ++ih)
#pragma unroll
        for (int i = 0; i < 4; ++i)
#pragma unroll
          for (int jh = 0; jh < 2; ++jh)
#pragma unroll
            for (int j = 0; j < 4; ++j)
              acc[ih * 4 + i][jh * 4 + j] =
                  fmaf(a[ih][i], w[jh][j], acc[ih * 4 + i][jh * 4 + j]);
    }
    __syncthreads();
  }

#pragma unroll
  for (int ih = 0; ih < 2; ++ih)
#pragma unroll
    for (int i = 0; i < 4; ++i) {
      const int rr = row0 + ih * (BM / 2) + ty * 4 + i;
#pragma unroll
      for (int jh = 0; jh < 2; ++jh) {
        int c = col0 + jh * (BN / 2) + tx * 4;
        float4 v = make_float4(acc[ih * 4 + i][jh * 4 + 0],
                               acc[ih * 4 + i][jh * 4 + 1],
                               acc[ih * 4 + i][jh * 4 + 2],
                               acc[ih * 4 + i][jh * 4 + 3]);
        if (HASBIAS) {
          v.x += bias[c + 0]; v.y += bias[c + 1];
          v.z += bias[c + 2]; v.w += bias[c + 3];
        }
        if (RELU) {
          v.x = fmaxf(v.x, 0.f); v.y = fmaxf(v.y, 0.f);
          v.z = fmaxf(v.z, 0.f); v.w = fmaxf(v.w, 0.f);
        }
        if (OUTMODE == 2) {
          float vv[4] = {v.x, v.y, v.z, v.w};
          size_t ps = (size_t)pitchM * N;
#pragma unroll
          for (int j = 0; j < 4; ++j) {
            short s0, s1; split2h(vv[j], s0, s1);
            int cc = c + j;
            size_t o = ((size_t)(cc >> 5) * pitchM + rr) * 32 + (cc & 31);
            osplit[o] = s0; osplit[o + ps] = s1;
          }
        } else {
          *reinterpret_cast<float4*>(&C[(size_t)rr * N + c]) = v;
        }
      }
    }
}

// ---------------------------------------------------------------------------
// W2 (256x512) + W3 (512x768) -> 2-limb f16 k-tiled planes, one kernel.
// ---------------------------------------------------------------------------
__global__ __launch_bounds__(256) void presplit_w2x2(
    const float* __restrict__ A, const float* __restrict__ B,
    short* __restrict__ oA, short* __restrict__ oB)
{
  const int tA = 256 * 512, tB = 512 * 768;
  for (int idx = blockIdx.x * 256 + threadIdx.x; idx < tA + tB;
       idx += gridDim.x * 256) {
    if (idx < tA) {
      int k = idx / 512, n = idx - k * 512;
      short s0, s1; split2h(A[idx], s0, s1);
      size_t o = ((size_t)(k >> 5) * 512 + n) * 32 + (k & 31);
      oA[o] = s0; oA[o + tA] = s1;
    } else {
      int e = idx - tA;
      int k = e / 768, n = e - k * 768;
      short s0, s1; split2h(B[e], s0, s1);
      size_t o = ((size_t)(k >> 5) * 768 + n) * 32 + (k & 31);
      oB[o] = s0; oB[o + tB] = s1;
    }
  }
}

// legacy single-matrix 2-limb presplit (Path B)
__global__ __launch_bounds__(256) void presplit_w2(
    const float* __restrict__ W, short* __restrict__ out, int K, int N)
{
  const int total = K * N;
  const size_t ps = (size_t)K * N;
  for (int idx = blockIdx.x * 256 + threadIdx.x; idx < total;
       idx += gridDim.x * 256) {
    int k = idx / N, n = idx - k * N;
    short s0, s1; split2h(W[idx], s0, s1);
    size_t o = ((size_t)(k >> 5) * N + n) * 32 + (k & 31);
    out[o] = s0; out[o + ps] = s1;
  }
}

// three 768x768 matrices -> 1-plane f16 k-tiled (value-only path weights)
__global__ __launch_bounds__(256) void presplit_w1x3(
    const float* __restrict__ A, const float* __restrict__ B,
    const float* __restrict__ C,
    short* __restrict__ oA, short* __restrict__ oB, short* __restrict__ oC)
{
  const int total = 768 * 768;
  for (int idx = blockIdx.x * 256 + threadIdx.x; idx < 3 * total;
       idx += gridDim.x * 256) {
    int seg = idx / total, e = idx - seg * total;
    const float* src = (seg == 0) ? A : ((seg == 1) ? B : C);
    short* dst = (seg == 0) ? oA : ((seg == 1) ? oB : oC);
    int k = e / 768, n = e - k * 768;
    size_t o = ((size_t)(k >> 5) * 768 + n) * 32 + (k & 31);
    dst[o] = (short)f2h(src[e]);
  }
}

// ---------------------------------------------------------------------------
// Fold scores weights through W4 (fused 2-limb f16 split) + bias2.
// grid 769: blocks 0..767 -> Ws2 rows; block 768 -> bias2.
// ---------------------------------------------------------------------------
__global__ __launch_bounds__(128) void fold_ws2(
    const float* __restrict__ W4, const float* __restrict__ selw,
    short* __restrict__ Ws2s, const float* __restrict__ b4,
    float* __restrict__ bias2)
{
  const int i = blockIdx.x;
  const int k = threadIdx.x;
  if (i == 768) {
    float s = 0.0f;
    for (int d = 0; d < 768; ++d)
      s = fmaf(b4[d], selw[(size_t)k * 768 + d], s);
    bias2[k] = s;
    return;
  }
  __shared__ float w4row[768];
  for (int j = k; j < 768; j += 128) w4row[j] = W4[(size_t)i * 768 + j];
  __syncthreads();
  float acc = 0.0f;
  const float* sr = selw + (size_t)k * 768;
#pragma unroll 8
  for (int j = 0; j < 768; ++j) acc = fmaf(w4row[j], sr[j], acc);
  short s0, s1; split2h(acc, s0, s1);
  const size_t ps = (size_t)768 * 128;
  size_t o = ((size_t)(i >> 5) * 128 + k) * 32 + (i & 31);
  Ws2s[o] = s0; Ws2s[o + ps] = s1;
}

// ---------------------------------------------------------------------------
// MFMA GEMM, plane-input only.
// LIMBS=2: f16 2-limb scaled-residual, 3 MFMAs/ktile, dual accumulator.
// LIMBS=1: plain f16 (plane 0), 1 MFMA/ktile (value-only path).
// A planes [LIMBS][kfull/32][apitch][32]; optional rowmap gather.
// MODE 0: relu(+bias) -> split2h planes, pitch opitch, row offset r0
// MODE 1: (+bias if nonnull, opt RELUF) -> f32 rows [M][N]
// MODE 2: Path B combo (pf bf16 / scores f32 via W2g)
// MODE 4: (+bias) -> bf16 rows [M][N]
// MODE 5: relu(+bias) -> 1-plane f16 k-tiled, pitch opitch
// MODE 7: relu(+bias) -> split2h planes (pitch opitch, local row) AND
//         limb0 -> persistent 1-plane f16, global pitch 65536, offset r0.
// MODE 9: K-split scores partial: blockIdx.x = m-tile (col0), blockIdx.y =
//         K-slice (kb += y*K/32); raw f32 partial -> fout + y*N*128,
//         layout [k=row 0..127][m=col], no bias.
// ---------------------------------------------------------------------------
template<int MODE, int LIMBS, bool RELUF>
__global__ __launch_bounds__(256) void mfma_gemm(
    const void* __restrict__ Agv, const short* __restrict__ Wg,
    const short* __restrict__ W2g,
    const float* __restrict__ bias, const float* __restrict__ bias2,
    short* __restrict__ out_split, unsigned short* __restrict__ pfout,
    float* __restrict__ fout, int M, int N, int K, int r0,
    const int* __restrict__ rowmap,
    int kbase, int kfull, int apitch, int opitch)
{
  __shared__ __align__(16) short Als[LIMBS][128 * 32];
  __shared__ __align__(16) short Bls[LIMBS][128 * 32];

  const int tid = threadIdx.x;
  const int lane = tid & 63;
  const int wid = tid >> 6;
  const int wm = wid >> 1, wn = wid & 1;
  const int fr = lane & 15, kg = lane >> 4;
  const int row0 = (MODE == 9) ? 0 : blockIdx.x * 128;
  const bool SC = (MODE == 2) && ((int)blockIdx.y == (int)gridDim.y - 1);
  const short* Wsrc = SC ? W2g : Wg;
  const int Nw = SC ? 128 : N;
  const int col0 = SC ? 0
                      : ((MODE == 9) ? (int)blockIdx.x * 128
                                     : (int)blockIdx.y * 128);
  const short* Ag = (const short*)Agv;
  const size_t planeA = (size_t)apitch * kfull;
  const size_t planeW = (size_t)Nw * kfull;
  const int kb = (kbase >> 5) +
                 ((MODE == 9) ? (int)blockIdx.y * (K >> 5) : 0);
  float* fo9 = fout;
  if (MODE == 9) fo9 += (size_t)blockIdx.y * N * 128;

  const int su0 = tid, su1 = tid + 256;
  int ar0 = row0 + (su0 >> 2), ar1 = row0 + (su1 >> 2);
  if (rowmap) { ar0 = rowmap[ar0]; ar1 = rowmap[ar1]; }
  const int br0 = col0 + (su0 >> 2), br1 = col0 + (su1 >> 2);
  const int acol0 = (su0 & 3) * 8, acol1 = (su1 & 3) * 8;
  const int sb0 = SWZG(su0) * 8, sb1 = SWZG(su1) * 8;  // swizzled LDS bases

  f32x4 acc0[4][4];
  f32x4 accX[4][4];
#pragma unroll
  for (int i = 0; i < 4; ++i)
#pragma unroll
    for (int j = 0; j < 4; ++j) { acc0[i][j] = (f32x4)0.0f; accX[i][j] = (f32x4)0.0f; }

  const int nk = K >> 5;
  bf16x8 stA[LIMBS][2], stB[LIMBS][2];

  // initial prefetch (kt = 0)
#pragma unroll
  for (int s = 0; s < LIMBS; ++s) {
    const short* pa = Ag + (size_t)s * planeA + (size_t)kb * apitch * 32;
    const short* pb = Wsrc + (size_t)s * planeW + (size_t)kb * Nw * 32;
    stA[s][0] = *(const bf16x8*)(pa + (size_t)ar0 * 32 + acol0);
    stA[s][1] = *(const bf16x8*)(pa + (size_t)ar1 * 32 + acol1);
    stB[s][0] = *(const bf16x8*)(pb + (size_t)br0 * 32 + acol0);
    stB[s][1] = *(const bf16x8*)(pb + (size_t)br1 * 32 + acol1);
  }

  for (int kt = 0; kt < nk; ++kt) {
    __syncthreads();  // previous tile reads complete
    // --- write LDS (swizzled) ---
#pragma unroll
    for (int s = 0; s < LIMBS; ++s) {
      *(bf16x8*)(&Als[s][sb0]) = stA[s][0];
      *(bf16x8*)(&Als[s][sb1]) = stA[s][1];
      *(bf16x8*)(&Bls[s][sb0]) = stB[s][0];
      *(bf16x8*)(&Bls[s][sb1]) = stB[s][1];
    }
    // --- prefetch next tile ---
    if (kt + 1 < nk) {
#pragma unroll
      for (int s = 0; s < LIMBS; ++s) {
        const short* pa = Ag + (size_t)s * planeA +
                          (size_t)(kb + kt + 1) * apitch * 32;
        const short* pb = Wsrc + (size_t)s * planeW +
                          (size_t)(kb + kt + 1) * Nw * 32;
        stA[s][0] = *(const bf16x8*)(pa + (size_t)ar0 * 32 + acol0);
        stA[s][1] = *(const bf16x8*)(pa + (size_t)ar1 * 32 + acol1);
        stB[s][0] = *(const bf16x8*)(pb + (size_t)br0 * 32 + acol0);
        stB[s][1] = *(const bf16x8*)(pb + (size_t)br1 * 32 + acol1);
      }
    }
    __syncthreads();  // LDS writes visible

    if (LIMBS == 2) {
      f16x8 a0[4], b0[4];
#pragma unroll
      for (int t = 0; t < 4; ++t) {
        const int ga = ((wm * 64 + t * 16 + fr) << 2) | kg;
        const int gb = ((wn * 64 + t * 16 + fr) << 2) | kg;
        a0[t] = *(const f16x8*)(&Als[0][SWZG(ga) * 8]);
        b0[t] = *(const f16x8*)(&Bls[0][SWZG(gb) * 8]);
      }
#pragma unroll
      for (int mt = 0; mt < 4; ++mt)
#pragma unroll
        for (int nt = 0; nt < 4; ++nt)
          acc0[mt][nt] = __builtin_amdgcn_mfma_f32_16x16x32_f16(
              a0[mt], b0[nt], acc0[mt][nt], 0, 0, 0);
      f16x8 x1[4];
#pragma unroll
      for (int t = 0; t < 4; ++t) {
        const int gb = ((wn * 64 + t * 16 + fr) << 2) | kg;
        x1[t] = *(const f16x8*)(&Bls[LIMBS - 1][SWZG(gb) * 8]);
      }
#pragma unroll
      for (int mt = 0; mt < 4; ++mt)
#pragma unroll
        for (int nt = 0; nt < 4; ++nt)
          accX[mt][nt] = __builtin_amdgcn_mfma_f32_16x16x32_f16(
              a0[mt], x1[nt], accX[mt][nt], 0, 0, 0);
#pragma unroll
      for (int t = 0; t < 4; ++t) {
        const int ga = ((wm * 64 + t * 16 + fr) << 2) | kg;
        x1[t] = *(const f16x8*)(&Als[LIMBS - 1][SWZG(ga) * 8]);
      }
#pragma unroll
      for (int mt = 0; mt < 4; ++mt)
#pragma unroll
        for (int nt = 0; nt < 4; ++nt)
          accX[mt][nt] = __builtin_amdgcn_mfma_f32_16x16x32_f16(
              x1[mt], b0[nt], accX[mt][nt], 0, 0, 0);
    } else {
      f16x8 a0[4], b0[4];
#pragma unroll
      for (int t = 0; t < 4; ++t) {
        const int ga = ((wm * 64 + t * 16 + fr) << 2) | kg;
        const int gb = ((wn * 64 + t * 16 + fr) << 2) | kg;
        a0[t] = *(const f16x8*)(&Als[0][SWZG(ga) * 8]);
        b0[t] = *(const f16x8*)(&Bls[0][SWZG(gb) * 8]);
      }
#pragma unroll
      for (int mt = 0; mt < 4; ++mt)
#pragma unroll
        for (int nt = 0; nt < 4; ++nt)
          acc0[mt][nt] = __builtin_amdgcn_mfma_f32_16x16x32_f16(
              a0[mt], b0[nt], acc0[mt][nt], 0, 0, 0);
    }
  }

  // epilogue: C frag mapping col = lane&15, row = (lane>>4)*4 + r  [m89]
  const size_t psO = (size_t)opitch * N;
#pragma unroll
  for (int mt = 0; mt < 4; ++mt)
#pragma unroll
    for (int nt = 0; nt < 4; ++nt)
#pragma unroll
      for (int r = 0; r < 4; ++r) {
        int row = row0 + wm * 64 + mt * 16 + kg * 4 + r;
        int col = col0 + wn * 64 + nt * 16 + fr;
        float x = acc0[mt][nt][r];
        if (LIMBS == 2) x += accX[mt][nt][r] * 4.8828125e-4f;  // 2^-11
        if (MODE == 2) {
          if (SC) {
            fout[(size_t)row * 128 + col] = x + bias2[col];
          } else {
            pfout[(size_t)(r0 + row) * 768 + col] = f2bf(x + bias[col]);
          }
        } else if (MODE == 1) {
          if (bias) x += bias[col];
          if (RELUF) x = fmaxf(x, 0.0f);
          fout[(size_t)row * N + col] = x;
        } else if (MODE == 9) {
          fo9[(size_t)row * N + col] = x;
        } else if (MODE == 4) {
          pfout[(size_t)row * N + col] = f2bf(x + bias[col]);
        } else if (MODE == 5) {
          x = fmaxf(x + bias[col], 0.0f);
          size_t o = ((size_t)(col >> 5) * opitch + row) * 32 + (col & 31);
          out_split[o] = (short)f2h(x);
        } else if (MODE == 7) {
          x = fmaxf(x + bias[col], 0.0f);
          short s0, s1; split2h(x, s0, s1);
          size_t o = ((size_t)(col >> 5) * opitch + row) * 32 + (col & 31);
          out_split[o] = s0; out_split[o + psO] = s1;
          size_t op = ((size_t)(col >> 5) * 65536 + (r0 + row)) * 32 + (col & 31);
          ((short*)pfout)[op] = s0;
        } else {  // MODE 0
          x = fmaxf(x + bias[col], 0.0f);
          short s0, s1; split2h(x, s0, s1);
          size_t o = ((size_t)(col >> 5) * opitch + (r0 + row)) * 32 + (col & 31);
          out_split[o] = s0; out_split[o + psO] = s1;
        }
      }
}

// ---------------------------------------------------------------------------
// Combine 4 K-split score partials + bias2 + gumbel -> sgT.
// grid (cm/256, 128), block 256. scp layout [4][k=128][m=cm].
// ---------------------------------------------------------------------------
__global__ __launch_bounds__(256) void score_combine(
    const float* __restrict__ scp, const float* __restrict__ bias2,
    float* __restrict__ sgT, int cm, int r0)
{
  const int k = blockIdx.y;
  const int m = blockIdx.x * 256 + threadIdx.x;
  const size_t ps = (size_t)cm * 128;
  const size_t o = (size_t)k * cm + m;
  float x = scp[o] + scp[o + ps] + scp[o + 2 * ps] + scp[o + 3 * ps]
            + bias2[k];
  const int gm = r0 + m;
  const uint32_t idx = ((uint32_t)(gm >> 13) << 20) | ((uint32_t)k << 13) |
                       (uint32_t)(gm & 8191);
  sgT[idx] = x + gumbel_at(idx);
}

// ---------------------------------------------------------------------------
// Path B: scores [rows][128] f32 -> sgT[b][k][m] with fused Gumbel noise.
// ---------------------------------------------------------------------------
__global__ __launch_bounds__(256) void gumbel_transpose(
    const float* __restrict__ sc, float* __restrict__ sgT, int r0)
{
  __shared__ float tile[32][33];
  const int lm0 = blockIdx.x * 32;
  const int k0 = blockIdx.y * 32;
  const int tx = threadIdx.x, ty = threadIdx.y;
#pragma unroll
  for (int rr = ty; rr < 32; rr += 8)
    tile[rr][tx] = sc[(size_t)(lm0 + rr) * 128 + k0 + tx];
  __syncthreads();
#pragma unroll
  for (int rr = ty; rr < 32; rr += 8) {
    int k = k0 + rr;
    int gm = r0 + lm0 + tx;
    uint32_t idx = ((uint32_t)(gm >> 13) << 20) | ((uint32_t)k << 13) |
                   (uint32_t)(gm & 8191);
    sgT[idx] = tile[tx][rr] + gumbel_at(idx);
  }
}

// ---------------------------------------------------------------------------
// Per-(b,k) top-32 of sgT row — register-resident incremental tournament.
// ---------------------------------------------------------------------------
__global__ __launch_bounds__(256) void top_candidates(
    const float* __restrict__ sgT, u64* __restrict__ cand)
{
  const int q = blockIdx.x;
  const int tid = threadIdx.x;
  const int lane = tid & 63, wid = tid >> 6;
  __shared__ u64 wb[4];
  u64 pr[32];
  const float4* row4 = reinterpret_cast<const float4*>(sgT + (size_t)q * 8192);
#pragma unroll
  for (int j = 0; j < 8; ++j) {
    float4 v = row4[tid + j * 256];
    const int mb = (tid + j * 256) * 4;
    pr[j * 4 + 0] = ((u64)fmono(v.x) << 13) | (u64)(8191 - (mb + 0));
    pr[j * 4 + 1] = ((u64)fmono(v.y) << 13) | (u64)(8191 - (mb + 1));
    pr[j * 4 + 2] = ((u64)fmono(v.z) << 13) | (u64)(8191 - (mb + 2));
    pr[j * 4 + 3] = ((u64)fmono(v.w) << 13) | (u64)(8191 - (mb + 3));
  }
  u64 lmax = 0;
#pragma unroll
  for (int r = 0; r < 32; ++r) if (pr[r] > lmax) lmax = pr[r];

  for (int it = 0; it < 32; ++it) {
    u64 loc = lmax;
#pragma unroll
    for (int off = 32; off; off >>= 1) {
      u64 o = __shfl_down(loc, off);
      if (o > loc) loc = o;
    }
    if (lane == 0) wb[wid] = loc;
    __syncthreads();
    u64 w01 = (wb[0] > wb[1]) ? wb[0] : wb[1];
    u64 w23 = (wb[2] > wb[3]) ? wb[2] : wb[3];
    u64 winner = (w01 > w23) ? w01 : w23;
    __syncthreads();
    if (tid == 0) cand[(size_t)q * 32 + it] = winner;
    const int wmm = 8191 - (int)(winner & 0x1FFFull);
    if (((wmm >> 2) & 255) == tid) {
      const int orr = ((wmm >> 10) << 2) | (wmm & 3);
#pragma unroll
      for (int r = 0; r < 32; ++r) if (r == orr) pr[r] = 0;
      lmax = 0;
#pragma unroll
      for (int r = 0; r < 32; ++r) if (pr[r] > lmax) lmax = pr[r];
    }
  }
}

// ---------------------------------------------------------------------------
// Sequential resolve from LDS-resident candidate lists. grid (8), block 64.
// ---------------------------------------------------------------------------
__global__ __launch_bounds__(64) void resolve_kernel(
    const u64* __restrict__ cand, const float* __restrict__ sgT,
    int* __restrict__ sel)
{
  const int b = blockIdx.x;
  const int lane = threadIdx.x;
  __shared__ u64 candL[4096];
  __shared__ uint32_t avail[256];
  for (int j = lane; j < 4096; j += 64) candL[j] = cand[(size_t)b * 4096 + j];
#pragma unroll
  for (int j = lane; j < 256; j += 64) avail[j] = 0xFFFFFFFFu;
  __syncthreads();

  for (int k = 0; k < 128; ++k) {
    u64 c = (lane < 32) ? candL[k * 32 + lane] : 0ull;
    int m = 8191 - (int)(c & 0x1FFFull);
    bool av = (lane < 32) && ((avail[m >> 5] >> (m & 31)) & 1u);
    u64 bal = __ballot(av);
    int pick;
    if (bal) {
      int j = __builtin_ctzll(bal);
      pick = __shfl(m, j);
    } else {
      u64 best = 0ull;
      const float* row = sgT + (size_t)(b * 128 + k) * 8192;
      for (int mm = lane; mm < 8192; mm += 64) {
        if ((avail[mm >> 5] >> (mm & 31)) & 1u) {
          u64 p = ((u64)fmono(row[mm]) << 13) | (u64)(8191 - mm);
          if (p > best) best = p;
        }
      }
#pragma unroll
      for (int off = 32; off; off >>= 1) {
        u64 o = __shfl_down(best, off);
        if (o > best) best = o;
      }
      best = __shfl(best, 0);
      pick = 8191 - (int)(best & 0x1FFFull);
    }
    if (lane == 0) {
      sel[b * 128 + k] = pick;
      avail[pick >> 5] &= ~(1u << (pick & 31));
    }
    __syncthreads();
  }
}

// ---------------------------------------------------------------------------
// KNN: d2 to 8192 points (LDS), 16 argmin passes.
// POOL=true: fused max-pool from full pf (bf16), split2h planes out (Path B).
// POOL=false: write rowlist directly (Path A).
// ---------------------------------------------------------------------------
template<bool POOL>
__global__ __launch_bounds__(256) void knn_kernel(
    const float* __restrict__ coords,
    const __hip_bfloat16* __restrict__ pf,
    const int* __restrict__ sel_idx,
    short* __restrict__ pooled_s,
    int* __restrict__ rowlist_g)
{
  const int q = blockIdx.x;
  const int b = q >> 7;
  const int tid = threadIdx.x;
  const int lane = tid & 63, wid = tid >> 6;
  __shared__ float d2s[8192];
  __shared__ int nbrs[16];
  __shared__ u64 wb[4];

  const int sidx = sel_idx[q];
  const float* cbase = coords + (size_t)b * 8192 * 5;
  const float cx = cbase[sidx * 5 + 1];
  const float cy = cbase[sidx * 5 + 2];
  const float cz = cbase[sidx * 5 + 3];
  const float ss = cx * cx + cy * cy + cz * cz;

  for (int j = 0; j < 32; ++j) {
    int m = tid + j * 256;
    float px = cbase[m * 5 + 1], py = cbase[m * 5 + 2], pz = cbase[m * 5 + 3];
    d2s[m] = ss + (px * px + py * py + pz * pz)
               - 2.0f * (cx * px + cy * py + cz * pz);
  }
  __syncthreads();

  for (int it = 0; it < 16; ++it) {
    u64 loc = ~0ull;
    for (int j = 0; j < 32; ++j) {
      int m = tid + j * 256;
      u64 p = ((u64)fmono(d2s[m]) << 13) | (u64)m;
      if (p < loc) loc = p;
    }
#pragma unroll
    for (int off = 32; off; off >>= 1) {
      u64 o = __shfl_down(loc, off);
      if (o < loc) loc = o;
    }
    if (lane == 0) wb[wid] = loc;
    __syncthreads();
    if (tid == 0) {
      u64 best = wb[0];
      if (wb[1] < best) best = wb[1];
      if (wb[2] < best) best = wb[2];
      if (wb[3] < best) best = wb[3];
      int m = (int)(best & 0x1FFFull);
      nbrs[it] = m;
      d2s[m] = __uint_as_float(0x7F800000u);
    }
    __syncthreads();
  }

  if (POOL) {
    const size_t ps = (size_t)1024 * 768;
    for (int d = tid; d < 768; d += 256) {
      float mx = -__uint_as_float(0x7F800000u);
#pragma unroll
      for (int it = 0; it < 16; ++it) {
        float v = __bfloat162float(pf[((size_t)b * 8192 + nbrs[it]) * 768 + d]);
        mx = fmaxf(mx, v);
      }
      short s0, s1; split2h(mx, s0, s1);
      size_t o = ((size_t)(d >> 5) * 1024 + q) * 32 + (d & 31);
      pooled_s[o] = s0; pooled_s[o + ps] = s1;
    }
  } else {
    if (tid < 16) rowlist_g[1024 + q * 16 + tid] = b * 8192 + nbrs[tid];
    if (tid == 16) rowlist_g[q] = b * 8192 + sidx;
  }
}

// pooled (1-plane f16 k-tiled) from pf_sub neighbor rows. grid (1024).
__global__ __launch_bounds__(256) void pool_from_sub(
    const unsigned short* __restrict__ pf_sub, short* __restrict__ pooled_s)
{
  const int q = blockIdx.x;
  const int tid = threadIdx.x;
  const unsigned short* base = pf_sub + (size_t)(1024 + q * 16) * 768;
  for (int d = tid; d < 768; d += 256) {
    float mx = -__uint_as_float(0x7F800000u);
#pragma unroll
    for (int it = 0; it < 16; ++it)
      mx = fmaxf(mx, bfu2f(base[(size_t)it * 768 + d]));
    size_t o = ((size_t)(d >> 5) * 1024 + q) * 32 + (d & 31);
    pooled_s[o] = (short)f2h(mx);
  }
}

// ---------------------------------------------------------------------------
// Parallel finalize.
// ---------------------------------------------------------------------------
__global__ __launch_bounds__(128) void rank_cent(
    const float* __restrict__ coords, const int* __restrict__ sel_idx,
    int* __restrict__ rank_g, float* __restrict__ out)
{
  const int b = blockIdx.x;
  const int tid = threadIdx.x;
  __shared__ float tvals[128];
  const float* cbase = coords + (size_t)b * 8192 * 5;
  const int q = (b << 7) + tid;
  const int sidx = sel_idx[q];
  tvals[tid] = cbase[sidx * 5 + 4];
  __syncthreads();
  float t = tvals[tid];
  int r = 0;
#pragma unroll 8
  for (int j = 0; j < 128; ++j) {
    float tj = tvals[j];
    r += (tj < t || (tj == t && j < tid)) ? 1 : 0;
  }
  rank_g[q] = r;
  float* cent = out + 786432;
  float* mask = out + 786432 + 4096;
  cent[((b << 7) + r) * 4 + 0] = cbase[sidx * 5 + 1];
  cent[((b << 7) + r) * 4 + 1] = cbase[sidx * 5 + 2];
  cent[((b << 7) + r) * 4 + 2] = cbase[sidx * 5 + 3];
  cent[((b << 7) + r) * 4 + 3] = cbase[sidx * 5 + 4];
  mask[q] = 1.0f;
}

__global__ __launch_bounds__(192) void token_write(
    const unsigned short* __restrict__ feat, const float* __restrict__ agg,
    const int* __restrict__ rank_g, const int* __restrict__ selmap,
    float* __restrict__ out)
{
  const int b = blockIdx.x, i = blockIdx.y;
  const int q = (b << 7) + i;
  const int tid = threadIdx.x;
  const int r = rank_g[q];
  const unsigned short* src =
      selmap ? feat + ((size_t)b * 8192 + selmap[q]) * 768
             : feat + (size_t)q * 768;
  const float* asrc = agg + (size_t)q * 768;
  float* dst = out + ((size_t)(b << 7) + r) * 768;
  for (int d = tid; d < 768; d += 192)
    dst[d] = bfu2f(src[d]) + asrc[d];
}

// ---------------------------------------------------------------------------
// host launcher — Path A''' (deferred pf, K-split scores) when ws allows,
// else Path B.
// ---------------------------------------------------------------------------
extern "C" void kernel_launch(void* const* d_in, const int* in_sizes, int n_in,
                              void* d_out, int out_size, void* d_ws, size_t ws_size,
                              hipStream_t stream) {
  const float* coords = (const float*)d_in[0];
  const float* feats  = (const float*)d_in[1];
  const float* W1 = (const float*)d_in[2];  const float* b1 = (const float*)d_in[3];
  const float* W2 = (const float*)d_in[4];  const float* b2 = (const float*)d_in[5];
  const float* W3 = (const float*)d_in[6];  const float* b3 = (const float*)d_in[7];
  const float* W4 = (const float*)d_in[8];  const float* b4 = (const float*)d_in[9];
  const float* selw = (const float*)d_in[10];
  const float* nW1 = (const float*)d_in[11]; const float* nb1 = (const float*)d_in[12];
  const float* nW2 = (const float*)d_in[13]; const float* nb2 = (const float*)d_in[14];
  float* out = (float*)d_out;
  char* ws = (char*)d_ws;
  dim3 blk(256);

  // ---------------- Path A''' layout (persistent ~134.4 MiB) ----------------
  size_t a = 0;
  short* h3p0  = (short*)(ws + a);          a += (size_t)65536 * 768 * 2;   // 96MiB
  // union region: sgTa (32MiB) OVERLAPS pf_sub+pooled+t1+agg (33.03MB);
  // sgT dead after resolve_kernel, the others written after it.
  const size_t ua = a;
  float* sgTa  = (float*)(ws + ua);
  unsigned short* pf_sub = (unsigned short*)(ws + ua);
  short* pooled_a = (short*)(ws + ua + (size_t)17408 * 768 * 2);
  short* t1sa  = (short*)(ws + ua + (size_t)17408 * 768 * 2 + (size_t)1024 * 768 * 2);
  float* agga  = (float*)(ws + ua + (size_t)17408 * 768 * 2 + (size_t)2 * 1024 * 768 * 2);
  a += (size_t)33554432 + (size_t)1703936;  // 32MiB union + slack for pf tail
  short* W2sa  = (short*)(ws + a);          a += (size_t)2 * 256 * 512 * 2;
  short* W3sa  = (short*)(ws + a);          a += (size_t)2 * 512 * 768 * 2;
  short* W4sa  = (short*)(ws + a);          a += (size_t)768 * 768 * 2;
  short* Ws2sa = (short*)(ws + a);          a += (size_t)2 * 768 * 128 * 2;
  short* nW1sa = (short*)(ws + a);          a += (size_t)768 * 768 * 2;
  short* nW2sa = (short*)(ws + a);          a += (size_t)768 * 768 * 2;
  float* bias2a = (float*)(ws + a);         a += 512;
  u64*   canda = (u64*)(ws + a);            a += (size_t)1024 * 32 * 8;
  int*   sela  = (int*)(ws + a);            a += 4096;
  int*   rowlist = (int*)(ws + a);          a += (size_t)17408 * 4;
  int*   rank_a = (int*)(ws + a);           a += 4096;
  a = (a + 255) & ~(size_t)255;
  const size_t tmpA = a;

  // chunk temps (5120 B/row): h2s [0,2048), h1s/h3c [2048,5120) (h3c
  // overlaps h1s, dead after L2). scp (K-split partials, 2048 B/row) after.
  int McA = 0;
  {
    const int mc[4] = {16384, 8192, 4096, 2048};
    for (int ci = 0; ci < 4; ++ci)
      if (tmpA + (size_t)7168 * mc[ci] <= ws_size) { McA = mc[ci]; break; }
  }

  if (McA) {
    // =========================== PATH A''' ===========================
    short* h2s = (short*)(ws + tmpA);
    short* h1s = (short*)(ws + tmpA + (size_t)2048 * McA);
    short* h3c = (short*)(ws + tmpA + (size_t)2048 * McA);  // overlaps h1s
    float* scp = (float*)(ws + tmpA + (size_t)5120 * McA);  // [4][128][cm]

    fold_ws2<<<dim3(769), dim3(128), 0, stream>>>(W4, selw, Ws2sa, b4, bias2a);
    presplit_w2x2<<<512, blk, 0, stream>>>(W2, W3, W2sa, W3sa);
    presplit_w1x3<<<512, blk, 0, stream>>>(W4, nW1, nW2, W4sa, nW1sa, nW2sa);

    for (int r0 = 0; r0 < 65536; r0 += McA) {
      const int cm = McA;
      gemm_kernel<128,128,16,256,true ,false,true ,2>
        <<<dim3(cm/128, 2), blk, 0, stream>>>(feats + (size_t)r0 * 32, W1, b1,
                                              nullptr, cm, 256, 32, h1s, cm);
      mfma_gemm<0,2,false><<<dim3(cm/128, 4), blk, 0, stream>>>(
          h1s, W2sa, nullptr, b2, nullptr, h2s, nullptr, nullptr,
          cm, 512, 256, 0, nullptr, 0, 256, cm, cm);
      // L3: chunk 2-limb planes (for scores) + persistent limb0 plane
      mfma_gemm<7,2,false><<<dim3(cm/128, 6), blk, 0, stream>>>(
          h2s, W3sa, nullptr, b3, nullptr, h3c,
          (unsigned short*)h3p0, nullptr,
          cm, 768, 512, r0, nullptr, 0, 512, cm, cm);
      // K-split scores partials: grid (m-tiles, 4 K-slices) = 512 blocks
      mfma_gemm<9,2,false><<<dim3(cm/128, 4), blk, 0, stream>>>(
          Ws2sa, h3c, nullptr, nullptr, nullptr, nullptr, nullptr,
          scp, 128, cm, 192, 0, nullptr, 0, 768, 128, 0);
      // combine partials + bias2 + gumbel -> sgT
      score_combine<<<dim3(cm/256, 128), blk, 0, stream>>>(
          scp, bias2a, sgTa, cm, r0);
    }

    top_candidates<<<dim3(1024), blk, 0, stream>>>(sgTa, canda);
    resolve_kernel<<<dim3(8), dim3(64), 0, stream>>>(canda, sgTa, sela);
    knn_kernel<false><<<dim3(1024), blk, 0, stream>>>(
        coords, nullptr, sela, nullptr, rowlist);
    // gathered L4 from persistent h3 limb0 (f16), 1-limb value path
    mfma_gemm<4,1,false><<<dim3(136, 6), blk, 0, stream>>>(
        h3p0, W4sa, nullptr, b4, nullptr, nullptr, pf_sub, nullptr,
        17408, 768, 768, 0, rowlist, 0, 768, 65536, 0);
    pool_from_sub<<<dim3(1024), blk, 0, stream>>>(pf_sub, pooled_a);
    mfma_gemm<5,1,false><<<dim3(8, 6), blk, 0, stream>>>(
        pooled_a, nW1sa, nullptr, nb1, nullptr, t1sa, nullptr, nullptr,
        1024, 768, 768, 0, nullptr, 0, 768, 1024, 1024);
    mfma_gemm<1,1,false><<<dim3(8, 6), blk, 0, stream>>>(
        t1sa, nW2sa, nullptr, nb2, nullptr, nullptr, nullptr, agga,
        1024, 768, 768, 0, nullptr, 0, 768, 1024, 0);
    rank_cent<<<dim3(8), dim3(128), 0, stream>>>(coords, sela, rank_a, out);
    token_write<<<dim3(8, 128), dim3(192), 0, stream>>>(
        pf_sub, agga, rank_a, nullptr, out);
    return;
  }

  // =========================== PATH B (fallback) ===========================
  size_t off = 0;
  unsigned short* pf = (unsigned short*)(ws + off); off += (size_t)65536 * 768 * 2;
  float* sgT   = (float*)(ws + off);  off += (size_t)8 * 128 * 8192 * 4;
  short* W2s   = (short*)(ws + off);  off += (size_t)2 * 256 * 512 * 2;
  short* W3s   = (short*)(ws + off);  off += (size_t)2 * 512 * 768 * 2;
  short* W4s   = (short*)(ws + off);  off += (size_t)2 * 768 * 768 * 2;
  short* Ws2s  = (short*)(ws + off);  off += (size_t)2 * 768 * 128 * 2;
  short* nW1s  = (short*)(ws + off);  off += (size_t)2 * 768 * 768 * 2;
  short* nW2s  = (short*)(ws + off);  off += (size_t)2 * 768 * 768 * 2;
  float* bias2 = (float*)(ws + off);  off += 512;
  short* pooled_s = (short*)(ws + off); off += (size_t)2 * 1024 * 768 * 2;
  short* t1s   = (short*)(ws + off);  off += (size_t)2 * 1024 * 768 * 2;
  float* agg   = (float*)(ws + off);  off += (size_t)1024 * 768 * 4;
  u64*   cand  = (u64*)(ws + off);    off += (size_t)1024 * 32 * 8;
  int*   sel   = (int*)(ws + off);    off += 4096;
  int*   rank_g = (int*)(ws + off);   off += 4096;
  off = (off + 255) & ~(size_t)255;
  const size_t tmp_off = off;

  int Mc = 512;
  const int mcand[6] = {16384, 8192, 4096, 2048, 1024, 512};
  for (int ci = 0; ci < 6; ++ci) {
    if (tmp_off + (size_t)5120 * mcand[ci] <= ws_size) { Mc = mcand[ci]; break; }
  }
  short* tA = (short*)(ws + tmp_off);                       // h2s (2048 B/row)
  short* tB = (short*)(ws + tmp_off + (size_t)2048 * Mc);   // h1s/h3s (3072 B/row)
  float* scc = (float*)tA;  // alias: h2s dead after L3

  fold_ws2<<<dim3(769), dim3(128), 0, stream>>>(W4, selw, Ws2s, b4, bias2);
  presplit_w2x2<<<512, blk, 0, stream>>>(W2, W3, W2s, W3s);
  presplit_w2<<<256, blk, 0, stream>>>(W4, W4s, 768, 768);
  presplit_w2<<<256, blk, 0, stream>>>(nW1, nW1s, 768, 768);
  presplit_w2<<<256, blk, 0, stream>>>(nW2, nW2s, 768, 768);

  for (int r0 = 0; r0 < 65536; r0 += Mc) {
    const int cm = (65536 - r0 < Mc) ? (65536 - r0) : Mc;
    short* h1s = tB;
    short* h2s = tA;
    short* h3s = tB;  // alias: h1s dead after L2
    gemm_kernel<128,128,16,256,true ,false,true ,2>
      <<<dim3(cm/128, 2), blk, 0, stream>>>(feats + (size_t)r0 * 32, W1, b1,
                                            nullptr, cm, 256, 32, h1s, cm);
    mfma_gemm<0,2,false><<<dim3(cm/128, 4), blk, 0, stream>>>(
        h1s, W2s, nullptr, b2, nullptr, h2s, nullptr, nullptr,
        cm, 512, 256, 0, nullptr, 0, 256, cm, cm);
    mfma_gemm<0,2,false><<<dim3(cm/128, 6), blk, 0, stream>>>(
        h2s, W3s, nullptr, b3, nullptr, h3s, nullptr, nullptr,
        cm, 768, 512, 0, nullptr, 0, 512, cm, cm);
    mfma_gemm<2,2,false><<<dim3(cm/128, 7), blk, 0, stream>>>(
        h3s, W4s, Ws2s, b4, bias2, nullptr, pf, scc,
        cm, 768, 768, r0, nullptr, 0, 768, cm, 0);
    gumbel_transpose<<<dim3(cm/32, 4), dim3(32, 8), 0, stream>>>(scc, sgT, r0);
  }

  top_candidates<<<dim3(1024), blk, 0, stream>>>(sgT, cand);
  resolve_kernel<<<dim3(8), dim3(64), 0, stream>>>(cand, sgT, sel);
  knn_kernel<true ><<<dim3(1024), blk, 0, stream>>>(
      coords, (const __hip_bfloat16*)pf, sel, pooled_s, nullptr);
  mfma_gemm<0,2,false><<<dim3(8, 6), blk, 0, stream>>>(
      pooled_s, nW1s, nullptr, nb1, nullptr, t1s, nullptr, nullptr,
      1024, 768, 768, 0, nullptr, 0, 768, 1024, 1024);
  mfma_gemm<1,2,false><<<dim3(8, 6), blk, 0, stream>>>(
      t1s, nW2s, nullptr, nb2, nullptr, nullptr, nullptr, agg,
      1024, 768, 768, 0, nullptr, 0, 768, 1024, 0);
  rank_cent<<<dim3(8), dim3(128), 0, stream>>>(coords, sel, rank_g, out);
  token_write<<<dim3(8, 128), dim3(192), 0, stream>>>(
      pf, agg, rank_g, sel, out);
}

// Round 17
// 828.852 us; speedup vs baseline: 1.5244x; 1.0462x over previous
//
#include <hip/hip_runtime.h>
#include <hip/hip_bf16.h>
#include <hip/hip_fp16.h>
#include <stdint.h>
#include <stddef.h>

typedef unsigned long long u64;
typedef __attribute__((ext_vector_type(8))) short bf16x8;
typedef __attribute__((ext_vector_type(8))) _Float16 f16x8;
typedef __attribute__((ext_vector_type(4))) float f32x4;

// LDS XOR swizzle in 16B granules (bank-spread for b128 write + frag read)
#define SWZG(g) ((g) ^ (((g) >> 2) & 7))

// ---------------------------------------------------------------------------
// Threefry-2x32-20 (JAX), key = (0, 42)  [verified bit-exact in round 2]
// ---------------------------------------------------------------------------
__device__ __forceinline__ uint32_t rotl32(uint32_t x, int r) {
  return (x << r) | (x >> (32 - r));
}

__device__ __forceinline__ void threefry2x32(uint32_t x0, uint32_t x1,
                                             uint32_t& o0, uint32_t& o1) {
  const uint32_t k0 = 0u, k1 = 42u;
  const uint32_t k2 = k0 ^ k1 ^ 0x1BD11BDAu;
  x0 += k0; x1 += k1;
#define TF_ROUND(r) { x0 += x1; x1 = rotl32(x1, (r)); x1 ^= x0; }
  TF_ROUND(13) TF_ROUND(15) TF_ROUND(26) TF_ROUND(6)
  x0 += k1; x1 += k2 + 1u;
  TF_ROUND(17) TF_ROUND(29) TF_ROUND(16) TF_ROUND(24)
  x0 += k2; x1 += k0 + 2u;
  TF_ROUND(13) TF_ROUND(15) TF_ROUND(26) TF_ROUND(6)
  x0 += k0; x1 += k1 + 3u;
  TF_ROUND(17) TF_ROUND(29) TF_ROUND(16) TF_ROUND(24)
  x0 += k1; x1 += k2 + 4u;
  TF_ROUND(13) TF_ROUND(15) TF_ROUND(26) TF_ROUND(6)
  x0 += k2; x1 += k0 + 5u;
#undef TF_ROUND
  o0 = x0; o1 = x1;
}

__device__ __forceinline__ float gumbel_at(uint32_t i) {
  uint32_t o0, o1;
  threefry2x32(0u, i, o0, o1);
  uint32_t bits = o0 ^ o1;
  float f = __uint_as_float((bits >> 9) | 0x3F800000u) - 1.0f;  // [0,1)
  float u = fmaxf(1e-20f, f + 1e-20f);
  return -logf(-logf(u));
}

// monotonic float->uint mapping (IEEE total order for finite values)
__device__ __forceinline__ uint32_t fmono(float v) {
  uint32_t b = __float_as_uint(v);
  return (b & 0x80000000u) ? ~b : (b | 0x80000000u);
}

__device__ __forceinline__ unsigned short f2bf(float x) {
  __hip_bfloat16 h = __float2bfloat16(x);
  return *reinterpret_cast<unsigned short*>(&h);
}

__device__ __forceinline__ float bfu2f(unsigned short v) {
  __hip_bfloat16 h = *reinterpret_cast<__hip_bfloat16*>(&v);
  return __bfloat162float(h);
}

__device__ __forceinline__ unsigned short f2h(float x) {
  __half h = __float2half(x);
  return *reinterpret_cast<unsigned short*>(&h);
}

// 2-limb f16 split with scaled residual: x ~= s0 + s1/2048, err ~2^-22|x|.
// s0 forced to 0 when f16(x) would be subnormal -> denormal-mode-robust.
__device__ __forceinline__ void split2h(float x, short& s0, short& s1) {
  float f0 = 0.0f;
  unsigned short u0 = 0;
  if (fabsf(x) >= 6.2e-5f) {
    __half h0 = __float2half(x);
    f0 = __half2float(h0);
    u0 = *reinterpret_cast<unsigned short*>(&h0);
  }
  __half h1 = __float2half((x - f0) * 2048.0f);
  s0 = (short)u0;
  s1 = *reinterpret_cast<short*>(&h1);
}

// ---------------------------------------------------------------------------
// f32 SIMT GEMM (conflict-free 4+4 split tile). Used only for L1 (K=32).
// OUTMODE 2: relu+split2h -> k-tiled planes [2][N/32][M][32].
// ---------------------------------------------------------------------------
template<int BM, int BN, int BK, int THREADS, bool RELU, bool BT, bool HASBIAS,
         int OUTMODE>
__global__ __launch_bounds__(THREADS) void gemm_kernel(
    const float* __restrict__ A, const float* __restrict__ W,
    const float* __restrict__ bias, float* __restrict__ C,
    int M, int N, int K, short* __restrict__ osplit, int pitchM)
{
  __shared__ __align__(16) float As[BK][BM + 4];
  __shared__ __align__(16) float Ws[BK][BN + 4];
  constexpr int TX = BN / 8;
  constexpr int TY = BM / 8;
  static_assert(TX * TY == THREADS, "bad tiling");
  constexpr int KV = BK / 4;

  const int tid = threadIdx.x;
  const int tx = tid % TX, ty = tid / TX;
  const int row0 = blockIdx.x * BM, col0 = blockIdx.y * BN;

  float acc[8][8];
#pragma unroll
  for (int i = 0; i < 8; ++i)
#pragma unroll
    for (int j = 0; j < 8; ++j) acc[i][j] = 0.0f;

  for (int k0 = 0; k0 < K; k0 += BK) {
#pragma unroll
    for (int e = tid; e < BM * KV; e += THREADS) {
      int m = e / KV, kq = e % KV;
      float4 v = *reinterpret_cast<const float4*>(
          &A[(size_t)(row0 + m) * K + k0 + kq * 4]);
      As[kq * 4 + 0][m] = v.x; As[kq * 4 + 1][m] = v.y;
      As[kq * 4 + 2][m] = v.z; As[kq * 4 + 3][m] = v.w;
    }
    if (BT) {
#pragma unroll
      for (int e = tid; e < BN * KV; e += THREADS) {
        int c = e / KV, kq = e % KV;
        float4 v = *reinterpret_cast<const float4*>(
            &W[(size_t)(col0 + c) * K + k0 + kq * 4]);
        Ws[kq * 4 + 0][c] = v.x; Ws[kq * 4 + 1][c] = v.y;
        Ws[kq * 4 + 2][c] = v.z; Ws[kq * 4 + 3][c] = v.w;
      }
    } else {
      constexpr int CV = BN / 4;
#pragma unroll
      for (int e = tid; e < BK * CV; e += THREADS) {
        int kk = e / CV, c4 = e % CV;
        float4 v = *reinterpret_cast<const float4*>(
            &W[(size_t)(k0 + kk) * N + col0 + c4 * 4]);
        *reinterpret_cast<float4*>(&Ws[kk][c4 * 4]) = v;
      }
    }
    __syncthreads();

#pragma unroll
    for (int kk = 0; kk < BK; ++kk) {
      float a[2][4], w[2][4];
      *reinterpret_cast<float4*>(a[0]) =
          *reinterpret_cast<const float4*>(&As[kk][ty * 4]);
      *reinterpret_cast<float4*>(a[1]) =
          *reinterpret_cast<const float4*>(&As[kk][BM / 2 + ty * 4]);
      *reinterpret_cast<float4*>(w[0]) =
          *reinterpret_cast<const float4*>(&Ws[kk][tx * 4]);
      *reinterpret_cast<float4*>(w[1]) =
          *reinterpret_cast<const float4*>(&Ws[kk][BN / 2 + tx * 4]);
#pragma unroll
      for (int ih = 0; ih < 2; ++ih)
#pragma unroll
        for (int i = 0; i < 4; ++i)
#pragma unroll
          for (int jh = 0; jh < 2; ++jh)
#pragma unroll
            for (int j = 0; j < 4; ++j)
              acc[ih * 4 + i][jh * 4 + j] =
                  fmaf(a[ih][i], w[jh][j], acc[ih * 4 + i][jh * 4 + j]);
    }
    __syncthreads();
  }

#pragma unroll
  for (int ih = 0; ih < 2; ++ih)
#pragma unroll
    for (int i = 0; i < 4; ++i) {
      const int rr = row0 + ih * (BM / 2) + ty * 4 + i;
#pragma unroll
      for (int jh = 0; jh < 2; ++jh) {
        int c = col0 + jh * (BN / 2) + tx * 4;
        float4 v = make_float4(acc[ih * 4 + i][jh * 4 + 0],
                               acc[ih * 4 + i][jh * 4 + 1],
                               acc[ih * 4 + i][jh * 4 + 2],
                               acc[ih * 4 + i][jh * 4 + 3]);
        if (HASBIAS) {
          v.x += bias[c + 0]; v.y += bias[c + 1];
          v.z += bias[c + 2]; v.w += bias[c + 3];
        }
        if (RELU) {
          v.x = fmaxf(v.x, 0.f); v.y = fmaxf(v.y, 0.f);
          v.z = fmaxf(v.z, 0.f); v.w = fmaxf(v.w, 0.f);
        }
        if (OUTMODE == 2) {
          float vv[4] = {v.x, v.y, v.z, v.w};
          size_t ps = (size_t)pitchM * N;
#pragma unroll
          for (int j = 0; j < 4; ++j) {
            short s0, s1; split2h(vv[j], s0, s1);
            int cc = c + j;
            size_t o = ((size_t)(cc >> 5) * pitchM + rr) * 32 + (cc & 31);
            osplit[o] = s0; osplit[o + ps] = s1;
          }
        } else {
          *reinterpret_cast<float4*>(&C[(size_t)rr * N + c]) = v;
        }
      }
    }
}

// ---------------------------------------------------------------------------
// W2 (256x512) + W3 (512x768) -> 2-limb f16 k-tiled planes, one kernel.
// ---------------------------------------------------------------------------
__global__ __launch_bounds__(256) void presplit_w2x2(
    const float* __restrict__ A, const float* __restrict__ B,
    short* __restrict__ oA, short* __restrict__ oB)
{
  const int tA = 256 * 512, tB = 512 * 768;
  for (int idx = blockIdx.x * 256 + threadIdx.x; idx < tA + tB;
       idx += gridDim.x * 256) {
    if (idx < tA) {
      int k = idx / 512, n = idx - k * 512;
      short s0, s1; split2h(A[idx], s0, s1);
      size_t o = ((size_t)(k >> 5) * 512 + n) * 32 + (k & 31);
      oA[o] = s0; oA[o + tA] = s1;
    } else {
      int e = idx - tA;
      int k = e / 768, n = e - k * 768;
      short s0, s1; split2h(B[e], s0, s1);
      size_t o = ((size_t)(k >> 5) * 768 + n) * 32 + (k & 31);
      oB[o] = s0; oB[o + tB] = s1;
    }
  }
}

// legacy single-matrix 2-limb presplit (Path B)
__global__ __launch_bounds__(256) void presplit_w2(
    const float* __restrict__ W, short* __restrict__ out, int K, int N)
{
  const int total = K * N;
  const size_t ps = (size_t)K * N;
  for (int idx = blockIdx.x * 256 + threadIdx.x; idx < total;
       idx += gridDim.x * 256) {
    int k = idx / N, n = idx - k * N;
    short s0, s1; split2h(W[idx], s0, s1);
    size_t o = ((size_t)(k >> 5) * N + n) * 32 + (k & 31);
    out[o] = s0; out[o + ps] = s1;
  }
}

// three 768x768 matrices -> 1-plane f16 k-tiled (value-only path weights)
__global__ __launch_bounds__(256) void presplit_w1x3(
    const float* __restrict__ A, const float* __restrict__ B,
    const float* __restrict__ C,
    short* __restrict__ oA, short* __restrict__ oB, short* __restrict__ oC)
{
  const int total = 768 * 768;
  for (int idx = blockIdx.x * 256 + threadIdx.x; idx < 3 * total;
       idx += gridDim.x * 256) {
    int seg = idx / total, e = idx - seg * total;
    const float* src = (seg == 0) ? A : ((seg == 1) ? B : C);
    short* dst = (seg == 0) ? oA : ((seg == 1) ? oB : oC);
    int k = e / 768, n = e - k * 768;
    size_t o = ((size_t)(k >> 5) * 768 + n) * 32 + (k & 31);
    dst[o] = (short)f2h(src[e]);
  }
}

// ---------------------------------------------------------------------------
// Fold scores weights through W4 (fused 2-limb f16 split) + bias2.
// grid 769: blocks 0..767 -> Ws2 rows; block 768 -> bias2.
// ---------------------------------------------------------------------------
__global__ __launch_bounds__(128) void fold_ws2(
    const float* __restrict__ W4, const float* __restrict__ selw,
    short* __restrict__ Ws2s, const float* __restrict__ b4,
    float* __restrict__ bias2)
{
  const int i = blockIdx.x;
  const int k = threadIdx.x;
  if (i == 768) {
    float s = 0.0f;
    for (int d = 0; d < 768; ++d)
      s = fmaf(b4[d], selw[(size_t)k * 768 + d], s);
    bias2[k] = s;
    return;
  }
  __shared__ float w4row[768];
  for (int j = k; j < 768; j += 128) w4row[j] = W4[(size_t)i * 768 + j];
  __syncthreads();
  float acc = 0.0f;
  const float* sr = selw + (size_t)k * 768;
#pragma unroll 8
  for (int j = 0; j < 768; ++j) acc = fmaf(w4row[j], sr[j], acc);
  short s0, s1; split2h(acc, s0, s1);
  const size_t ps = (size_t)768 * 128;
  size_t o = ((size_t)(i >> 5) * 128 + k) * 32 + (i & 31);
  Ws2s[o] = s0; Ws2s[o + ps] = s1;
}

// ---------------------------------------------------------------------------
// MFMA GEMM, plane-input only.
// LIMBS=2: f16 2-limb scaled-residual, 3 MFMAs/ktile, dual accumulator.
// LIMBS=1: plain f16 (plane 0), 1 MFMA/ktile (value-only path).
// A planes [LIMBS][kfull/32][apitch][32]; optional rowmap gather.
// MODE 0: relu(+bias) -> split2h planes, pitch opitch, row offset r0
// MODE 1: (+bias if nonnull, opt RELUF) -> f32 rows [M][N]
// MODE 2: Path B combo (pf bf16 / scores f32 via W2g)
// MODE 4: (+bias) -> bf16 rows [M][N]
// MODE 5: relu(+bias) -> 1-plane f16 k-tiled, pitch opitch
// MODE 7: relu(+bias) -> limb1 -> 1-plane chunk (pitch opitch, local row);
//         limb0 -> persistent 1-plane f16, global pitch 65536, offset r0.
// MODE 9: K-split scores partial: blockIdx.x = m-tile (col0), blockIdx.y =
//         K-slice (kb += y*K/32); raw f32 partial -> fout + y*N*128.
//         B limbs from SEPARATE buffers: limb0 = Wg (pitch wp0, caller
//         pre-offsets base), limb1 = W2g (pitch wp1).
// ---------------------------------------------------------------------------
template<int MODE, int LIMBS, bool RELUF>
__global__ __launch_bounds__(256) void mfma_gemm(
    const void* __restrict__ Agv, const short* __restrict__ Wg,
    const short* __restrict__ W2g,
    const float* __restrict__ bias, const float* __restrict__ bias2,
    short* __restrict__ out_split, unsigned short* __restrict__ pfout,
    float* __restrict__ fout, int M, int N, int K, int r0,
    const int* __restrict__ rowmap,
    int kbase, int kfull, int apitch, int opitch, int wp0, int wp1)
{
  __shared__ __align__(16) short Als[LIMBS][128 * 32];
  __shared__ __align__(16) short Bls[LIMBS][128 * 32];

  const int tid = threadIdx.x;
  const int lane = tid & 63;
  const int wid = tid >> 6;
  const int wm = wid >> 1, wn = wid & 1;
  const int fr = lane & 15, kg = lane >> 4;
  const int row0 = (MODE == 9) ? 0 : blockIdx.x * 128;
  const bool SC = (MODE == 2) && ((int)blockIdx.y == (int)gridDim.y - 1);
  const short* Wsrc = SC ? W2g : Wg;
  const int Nw = SC ? 128 : N;
  const int col0 = SC ? 0
                      : ((MODE == 9) ? (int)blockIdx.x * 128
                                     : (int)blockIdx.y * 128);
  const short* Ag = (const short*)Agv;
  const size_t planeA = (size_t)apitch * kfull;
  const size_t planeW = (size_t)Nw * kfull;
  const int kb = (kbase >> 5) +
                 ((MODE == 9) ? (int)blockIdx.y * (K >> 5) : 0);
  float* fo9 = fout;
  if (MODE == 9) fo9 += (size_t)blockIdx.y * N * 128;

  // per-limb B base/pitch (MODE 9 splits limbs across two buffers)
  const short* pbB0; const short* pbB1; int pbP0, pbP1;
  if (MODE == 9) { pbB0 = Wg; pbP0 = wp0; pbB1 = W2g; pbP1 = wp1; }
  else { pbB0 = Wsrc; pbP0 = Nw; pbB1 = Wsrc + planeW; pbP1 = Nw; }

  const int su0 = tid, su1 = tid + 256;
  int ar0 = row0 + (su0 >> 2), ar1 = row0 + (su1 >> 2);
  if (rowmap) { ar0 = rowmap[ar0]; ar1 = rowmap[ar1]; }
  const int br0 = col0 + (su0 >> 2), br1 = col0 + (su1 >> 2);
  const int acol0 = (su0 & 3) * 8, acol1 = (su1 & 3) * 8;
  const int sb0 = SWZG(su0) * 8, sb1 = SWZG(su1) * 8;  // swizzled LDS bases

  f32x4 acc0[4][4];
  f32x4 accX[4][4];
#pragma unroll
  for (int i = 0; i < 4; ++i)
#pragma unroll
    for (int j = 0; j < 4; ++j) { acc0[i][j] = (f32x4)0.0f; accX[i][j] = (f32x4)0.0f; }

  const int nk = K >> 5;
  bf16x8 stA[LIMBS][2], stB[LIMBS][2];

  // initial prefetch (kt = 0)
#pragma unroll
  for (int s = 0; s < LIMBS; ++s) {
    const short* pa = Ag + (size_t)s * planeA + (size_t)kb * apitch * 32;
    const short* pb = ((s == 0) ? pbB0 : pbB1) +
                      (size_t)kb * ((s == 0) ? pbP0 : pbP1) * 32;
    stA[s][0] = *(const bf16x8*)(pa + (size_t)ar0 * 32 + acol0);
    stA[s][1] = *(const bf16x8*)(pa + (size_t)ar1 * 32 + acol1);
    stB[s][0] = *(const bf16x8*)(pb + (size_t)br0 * 32 + acol0);
    stB[s][1] = *(const bf16x8*)(pb + (size_t)br1 * 32 + acol1);
  }

  for (int kt = 0; kt < nk; ++kt) {
    __syncthreads();  // previous tile reads complete
    // --- write LDS (swizzled) ---
#pragma unroll
    for (int s = 0; s < LIMBS; ++s) {
      *(bf16x8*)(&Als[s][sb0]) = stA[s][0];
      *(bf16x8*)(&Als[s][sb1]) = stA[s][1];
      *(bf16x8*)(&Bls[s][sb0]) = stB[s][0];
      *(bf16x8*)(&Bls[s][sb1]) = stB[s][1];
    }
    // --- prefetch next tile ---
    if (kt + 1 < nk) {
#pragma unroll
      for (int s = 0; s < LIMBS; ++s) {
        const short* pa = Ag + (size_t)s * planeA +
                          (size_t)(kb + kt + 1) * apitch * 32;
        const short* pb = ((s == 0) ? pbB0 : pbB1) +
                          (size_t)(kb + kt + 1) * ((s == 0) ? pbP0 : pbP1) * 32;
        stA[s][0] = *(const bf16x8*)(pa + (size_t)ar0 * 32 + acol0);
        stA[s][1] = *(const bf16x8*)(pa + (size_t)ar1 * 32 + acol1);
        stB[s][0] = *(const bf16x8*)(pb + (size_t)br0 * 32 + acol0);
        stB[s][1] = *(const bf16x8*)(pb + (size_t)br1 * 32 + acol1);
      }
    }
    __syncthreads();  // LDS writes visible

    if (LIMBS == 2) {
      f16x8 a0[4], b0[4];
#pragma unroll
      for (int t = 0; t < 4; ++t) {
        const int ga = ((wm * 64 + t * 16 + fr) << 2) | kg;
        const int gb = ((wn * 64 + t * 16 + fr) << 2) | kg;
        a0[t] = *(const f16x8*)(&Als[0][SWZG(ga) * 8]);
        b0[t] = *(const f16x8*)(&Bls[0][SWZG(gb) * 8]);
      }
#pragma unroll
      for (int mt = 0; mt < 4; ++mt)
#pragma unroll
        for (int nt = 0; nt < 4; ++nt)
          acc0[mt][nt] = __builtin_amdgcn_mfma_f32_16x16x32_f16(
              a0[mt], b0[nt], acc0[mt][nt], 0, 0, 0);
      f16x8 x1[4];
#pragma unroll
      for (int t = 0; t < 4; ++t) {
        const int gb = ((wn * 64 + t * 16 + fr) << 2) | kg;
        x1[t] = *(const f16x8*)(&Bls[LIMBS - 1][SWZG(gb) * 8]);
      }
#pragma unroll
      for (int mt = 0; mt < 4; ++mt)
#pragma unroll
        for (int nt = 0; nt < 4; ++nt)
          accX[mt][nt] = __builtin_amdgcn_mfma_f32_16x16x32_f16(
              a0[mt], x1[nt], accX[mt][nt], 0, 0, 0);
#pragma unroll
      for (int t = 0; t < 4; ++t) {
        const int ga = ((wm * 64 + t * 16 + fr) << 2) | kg;
        x1[t] = *(const f16x8*)(&Als[LIMBS - 1][SWZG(ga) * 8]);
      }
#pragma unroll
      for (int mt = 0; mt < 4; ++mt)
#pragma unroll
        for (int nt = 0; nt < 4; ++nt)
          accX[mt][nt] = __builtin_amdgcn_mfma_f32_16x16x32_f16(
              x1[mt], b0[nt], accX[mt][nt], 0, 0, 0);
    } else {
      f16x8 a0[4], b0[4];
#pragma unroll
      for (int t = 0; t < 4; ++t) {
        const int ga = ((wm * 64 + t * 16 + fr) << 2) | kg;
        const int gb = ((wn * 64 + t * 16 + fr) << 2) | kg;
        a0[t] = *(const f16x8*)(&Als[0][SWZG(ga) * 8]);
        b0[t] = *(const f16x8*)(&Bls[0][SWZG(gb) * 8]);
      }
#pragma unroll
      for (int mt = 0; mt < 4; ++mt)
#pragma unroll
        for (int nt = 0; nt < 4; ++nt)
          acc0[mt][nt] = __builtin_amdgcn_mfma_f32_16x16x32_f16(
              a0[mt], b0[nt], acc0[mt][nt], 0, 0, 0);
    }
  }

  // epilogue: C frag mapping col = lane&15, row = (lane>>4)*4 + r  [m89]
  const size_t psO = (size_t)opitch * N;
#pragma unroll
  for (int mt = 0; mt < 4; ++mt)
#pragma unroll
    for (int nt = 0; nt < 4; ++nt)
#pragma unroll
      for (int r = 0; r < 4; ++r) {
        int row = row0 + wm * 64 + mt * 16 + kg * 4 + r;
        int col = col0 + wn * 64 + nt * 16 + fr;
        float x = acc0[mt][nt][r];
        if (LIMBS == 2) x += accX[mt][nt][r] * 4.8828125e-4f;  // 2^-11
        if (MODE == 2) {
          if (SC) {
            fout[(size_t)row * 128 + col] = x + bias2[col];
          } else {
            pfout[(size_t)(r0 + row) * 768 + col] = f2bf(x + bias[col]);
          }
        } else if (MODE == 1) {
          if (bias) x += bias[col];
          if (RELUF) x = fmaxf(x, 0.0f);
          fout[(size_t)row * N + col] = x;
        } else if (MODE == 9) {
          fo9[(size_t)row * N + col] = x;
        } else if (MODE == 4) {
          pfout[(size_t)row * N + col] = f2bf(x + bias[col]);
        } else if (MODE == 5) {
          x = fmaxf(x + bias[col], 0.0f);
          size_t o = ((size_t)(col >> 5) * opitch + row) * 32 + (col & 31);
          out_split[o] = (short)f2h(x);
        } else if (MODE == 7) {
          x = fmaxf(x + bias[col], 0.0f);
          short s0, s1; split2h(x, s0, s1);
          // limb1 -> slim chunk buffer (single plane)
          size_t o = ((size_t)(col >> 5) * opitch + row) * 32 + (col & 31);
          out_split[o] = s1;
          // limb0 -> persistent global plane (the only copy)
          size_t op = ((size_t)(col >> 5) * 65536 + (r0 + row)) * 32 + (col & 31);
          ((short*)pfout)[op] = s0;
        } else {  // MODE 0
          x = fmaxf(x + bias[col], 0.0f);
          short s0, s1; split2h(x, s0, s1);
          size_t o = ((size_t)(col >> 5) * opitch + (r0 + row)) * 32 + (col & 31);
          out_split[o] = s0; out_split[o + psO] = s1;
        }
      }
}

// ---------------------------------------------------------------------------
// Combine 4 K-split score partials + bias2 + gumbel -> sgT.
// grid (cm/256, 128), block 256. scp layout [4][k=128][m=cm].
// ---------------------------------------------------------------------------
__global__ __launch_bounds__(256) void score_combine(
    const float* __restrict__ scp, const float* __restrict__ bias2,
    float* __restrict__ sgT, int cm, int r0)
{
  const int k = blockIdx.y;
  const int m = blockIdx.x * 256 + threadIdx.x;
  const size_t ps = (size_t)cm * 128;
  const size_t o = (size_t)k * cm + m;
  float x = scp[o] + scp[o + ps] + scp[o + 2 * ps] + scp[o + 3 * ps]
            + bias2[k];
  const int gm = r0 + m;
  const uint32_t idx = ((uint32_t)(gm >> 13) << 20) | ((uint32_t)k << 13) |
                       (uint32_t)(gm & 8191);
  sgT[idx] = x + gumbel_at(idx);
}

// ---------------------------------------------------------------------------
// Path B: scores [rows][128] f32 -> sgT[b][k][m] with fused Gumbel noise.
// ---------------------------------------------------------------------------
__global__ __launch_bounds__(256) void gumbel_transpose(
    const float* __restrict__ sc, float* __restrict__ sgT, int r0)
{
  __shared__ float tile[32][33];
  const int lm0 = blockIdx.x * 32;
  const int k0 = blockIdx.y * 32;
  const int tx = threadIdx.x, ty = threadIdx.y;
#pragma unroll
  for (int rr = ty; rr < 32; rr += 8)
    tile[rr][tx] = sc[(size_t)(lm0 + rr) * 128 + k0 + tx];
  __syncthreads();
#pragma unroll
  for (int rr = ty; rr < 32; rr += 8) {
    int k = k0 + rr;
    int gm = r0 + lm0 + tx;
    uint32_t idx = ((uint32_t)(gm >> 13) << 20) | ((uint32_t)k << 13) |
                   (uint32_t)(gm & 8191);
    sgT[idx] = tile[tx][rr] + gumbel_at(idx);
  }
}

// ---------------------------------------------------------------------------
// Per-(b,k) top-32 of sgT row — register-resident incremental tournament.
// ---------------------------------------------------------------------------
__global__ __launch_bounds__(256) void top_candidates(
    const float* __restrict__ sgT, u64* __restrict__ cand)
{
  const int q = blockIdx.x;
  const int tid = threadIdx.x;
  const int lane = tid & 63, wid = tid >> 6;
  __shared__ u64 wb[4];
  u64 pr[32];
  const float4* row4 = reinterpret_cast<const float4*>(sgT + (size_t)q * 8192);
#pragma unroll
  for (int j = 0; j < 8; ++j) {
    float4 v = row4[tid + j * 256];
    const int mb = (tid + j * 256) * 4;
    pr[j * 4 + 0] = ((u64)fmono(v.x) << 13) | (u64)(8191 - (mb + 0));
    pr[j * 4 + 1] = ((u64)fmono(v.y) << 13) | (u64)(8191 - (mb + 1));
    pr[j * 4 + 2] = ((u64)fmono(v.z) << 13) | (u64)(8191 - (mb + 2));
    pr[j * 4 + 3] = ((u64)fmono(v.w) << 13) | (u64)(8191 - (mb + 3));
  }
  u64 lmax = 0;
#pragma unroll
  for (int r = 0; r < 32; ++r) if (pr[r] > lmax) lmax = pr[r];

  for (int it = 0; it < 32; ++it) {
    u64 loc = lmax;
#pragma unroll
    for (int off = 32; off; off >>= 1) {
      u64 o = __shfl_down(loc, off);
      if (o > loc) loc = o;
    }
    if (lane == 0) wb[wid] = loc;
    __syncthreads();
    u64 w01 = (wb[0] > wb[1]) ? wb[0] : wb[1];
    u64 w23 = (wb[2] > wb[3]) ? wb[2] : wb[3];
    u64 winner = (w01 > w23) ? w01 : w23;
    __syncthreads();
    if (tid == 0) cand[(size_t)q * 32 + it] = winner;
    const int wmm = 8191 - (int)(winner & 0x1FFFull);
    if (((wmm >> 2) & 255) == tid) {
      const int orr = ((wmm >> 10) << 2) | (wmm & 3);
#pragma unroll
      for (int r = 0; r < 32; ++r) if (r == orr) pr[r] = 0;
      lmax = 0;
#pragma unroll
      for (int r = 0; r < 32; ++r) if (pr[r] > lmax) lmax = pr[r];
    }
  }
}

// ---------------------------------------------------------------------------
// Sequential resolve from LDS-resident candidate lists. grid (8), block 64.
// ---------------------------------------------------------------------------
__global__ __launch_bounds__(64) void resolve_kernel(
    const u64* __restrict__ cand, const float* __restrict__ sgT,
    int* __restrict__ sel)
{
  const int b = blockIdx.x;
  const int lane = threadIdx.x;
  __shared__ u64 candL[4096];
  __shared__ uint32_t avail[256];
  for (int j = lane; j < 4096; j += 64) candL[j] = cand[(size_t)b * 4096 + j];
#pragma unroll
  for (int j = lane; j < 256; j += 64) avail[j] = 0xFFFFFFFFu;
  __syncthreads();

  for (int k = 0; k < 128; ++k) {
    u64 c = (lane < 32) ? candL[k * 32 + lane] : 0ull;
    int m = 8191 - (int)(c & 0x1FFFull);
    bool av = (lane < 32) && ((avail[m >> 5] >> (m & 31)) & 1u);
    u64 bal = __ballot(av);
    int pick;
    if (bal) {
      int j = __builtin_ctzll(bal);
      pick = __shfl(m, j);
    } else {
      u64 best = 0ull;
      const float* row = sgT + (size_t)(b * 128 + k) * 8192;
      for (int mm = lane; mm < 8192; mm += 64) {
        if ((avail[mm >> 5] >> (mm & 31)) & 1u) {
          u64 p = ((u64)fmono(row[mm]) << 13) | (u64)(8191 - mm);
          if (p > best) best = p;
        }
      }
#pragma unroll
      for (int off = 32; off; off >>= 1) {
        u64 o = __shfl_down(best, off);
        if (o > best) best = o;
      }
      best = __shfl(best, 0);
      pick = 8191 - (int)(best & 0x1FFFull);
    }
    if (lane == 0) {
      sel[b * 128 + k] = pick;
      avail[pick >> 5] &= ~(1u << (pick & 31));
    }
    __syncthreads();
  }
}

// ---------------------------------------------------------------------------
// KNN: d2 to 8192 points (LDS), 16 argmin passes.
// POOL=true: fused max-pool from full pf (bf16), split2h planes out (Path B).
// POOL=false: write rowlist directly (Path A).
// ---------------------------------------------------------------------------
template<bool POOL>
__global__ __launch_bounds__(256) void knn_kernel(
    const float* __restrict__ coords,
    const __hip_bfloat16* __restrict__ pf,
    const int* __restrict__ sel_idx,
    short* __restrict__ pooled_s,
    int* __restrict__ rowlist_g)
{
  const int q = blockIdx.x;
  const int b = q >> 7;
  const int tid = threadIdx.x;
  const int lane = tid & 63, wid = tid >> 6;
  __shared__ float d2s[8192];
  __shared__ int nbrs[16];
  __shared__ u64 wb[4];

  const int sidx = sel_idx[q];
  const float* cbase = coords + (size_t)b * 8192 * 5;
  const float cx = cbase[sidx * 5 + 1];
  const float cy = cbase[sidx * 5 + 2];
  const float cz = cbase[sidx * 5 + 3];
  const float ss = cx * cx + cy * cy + cz * cz;

  for (int j = 0; j < 32; ++j) {
    int m = tid + j * 256;
    float px = cbase[m * 5 + 1], py = cbase[m * 5 + 2], pz = cbase[m * 5 + 3];
    d2s[m] = ss + (px * px + py * py + pz * pz)
               - 2.0f * (cx * px + cy * py + cz * pz);
  }
  __syncthreads();

  for (int it = 0; it < 16; ++it) {
    u64 loc = ~0ull;
    for (int j = 0; j < 32; ++j) {
      int m = tid + j * 256;
      u64 p = ((u64)fmono(d2s[m]) << 13) | (u64)m;
      if (p < loc) loc = p;
    }
#pragma unroll
    for (int off = 32; off; off >>= 1) {
      u64 o = __shfl_down(loc, off);
      if (o < loc) loc = o;
    }
    if (lane == 0) wb[wid] = loc;
    __syncthreads();
    if (tid == 0) {
      u64 best = wb[0];
      if (wb[1] < best) best = wb[1];
      if (wb[2] < best) best = wb[2];
      if (wb[3] < best) best = wb[3];
      int m = (int)(best & 0x1FFFull);
      nbrs[it] = m;
      d2s[m] = __uint_as_float(0x7F800000u);
    }
    __syncthreads();
  }

  if (POOL) {
    const size_t ps = (size_t)1024 * 768;
    for (int d = tid; d < 768; d += 256) {
      float mx = -__uint_as_float(0x7F800000u);
#pragma unroll
      for (int it = 0; it < 16; ++it) {
        float v = __bfloat162float(pf[((size_t)b * 8192 + nbrs[it]) * 768 + d]);
        mx = fmaxf(mx, v);
      }
      short s0, s1; split2h(mx, s0, s1);
      size_t o = ((size_t)(d >> 5) * 1024 + q) * 32 + (d & 31);
      pooled_s[o] = s0; pooled_s[o + ps] = s1;
    }
  } else {
    if (tid < 16) rowlist_g[1024 + q * 16 + tid] = b * 8192 + nbrs[tid];
    if (tid == 16) rowlist_g[q] = b * 8192 + sidx;
  }
}

// pooled (1-plane f16 k-tiled) from pf_sub neighbor rows. grid (1024).
__global__ __launch_bounds__(256) void pool_from_sub(
    const unsigned short* __restrict__ pf_sub, short* __restrict__ pooled_s)
{
  const int q = blockIdx.x;
  const int tid = threadIdx.x;
  const unsigned short* base = pf_sub + (size_t)(1024 + q * 16) * 768;
  for (int d = tid; d < 768; d += 256) {
    float mx = -__uint_as_float(0x7F800000u);
#pragma unroll
    for (int it = 0; it < 16; ++it)
      mx = fmaxf(mx, bfu2f(base[(size_t)it * 768 + d]));
    size_t o = ((size_t)(d >> 5) * 1024 + q) * 32 + (d & 31);
    pooled_s[o] = (short)f2h(mx);
  }
}

// ---------------------------------------------------------------------------
// Parallel finalize.
// ---------------------------------------------------------------------------
__global__ __launch_bounds__(128) void rank_cent(
    const float* __restrict__ coords, const int* __restrict__ sel_idx,
    int* __restrict__ rank_g, float* __restrict__ out)
{
  const int b = blockIdx.x;
  const int tid = threadIdx.x;
  __shared__ float tvals[128];
  const float* cbase = coords + (size_t)b * 8192 * 5;
  const int q = (b << 7) + tid;
  const int sidx = sel_idx[q];
  tvals[tid] = cbase[sidx * 5 + 4];
  __syncthreads();
  float t = tvals[tid];
  int r = 0;
#pragma unroll 8
  for (int j = 0; j < 128; ++j) {
    float tj = tvals[j];
    r += (tj < t || (tj == t && j < tid)) ? 1 : 0;
  }
  rank_g[q] = r;
  float* cent = out + 786432;
  float* mask = out + 786432 + 4096;
  cent[((b << 7) + r) * 4 + 0] = cbase[sidx * 5 + 1];
  cent[((b << 7) + r) * 4 + 1] = cbase[sidx * 5 + 2];
  cent[((b << 7) + r) * 4 + 2] = cbase[sidx * 5 + 3];
  cent[((b << 7) + r) * 4 + 3] = cbase[sidx * 5 + 4];
  mask[q] = 1.0f;
}

__global__ __launch_bounds__(192) void token_write(
    const unsigned short* __restrict__ feat, const float* __restrict__ agg,
    const int* __restrict__ rank_g, const int* __restrict__ selmap,
    float* __restrict__ out)
{
  const int b = blockIdx.x, i = blockIdx.y;
  const int q = (b << 7) + i;
  const int tid = threadIdx.x;
  const int r = rank_g[q];
  const unsigned short* src =
      selmap ? feat + ((size_t)b * 8192 + selmap[q]) * 768
             : feat + (size_t)q * 768;
  const float* asrc = agg + (size_t)q * 768;
  float* dst = out + ((size_t)(b << 7) + r) * 768;
  for (int d = tid; d < 768; d += 192)
    dst[d] = bfu2f(src[d]) + asrc[d];
}

// ---------------------------------------------------------------------------
// host launcher — Path A4 (deferred pf, K-split scores, no limb0 dup) when
// ws allows, else Path B.
// ---------------------------------------------------------------------------
extern "C" void kernel_launch(void* const* d_in, const int* in_sizes, int n_in,
                              void* d_out, int out_size, void* d_ws, size_t ws_size,
                              hipStream_t stream) {
  const float* coords = (const float*)d_in[0];
  const float* feats  = (const float*)d_in[1];
  const float* W1 = (const float*)d_in[2];  const float* b1 = (const float*)d_in[3];
  const float* W2 = (const float*)d_in[4];  const float* b2 = (const float*)d_in[5];
  const float* W3 = (const float*)d_in[6];  const float* b3 = (const float*)d_in[7];
  const float* W4 = (const float*)d_in[8];  const float* b4 = (const float*)d_in[9];
  const float* selw = (const float*)d_in[10];
  const float* nW1 = (const float*)d_in[11]; const float* nb1 = (const float*)d_in[12];
  const float* nW2 = (const float*)d_in[13]; const float* nb2 = (const float*)d_in[14];
  float* out = (float*)d_out;
  char* ws = (char*)d_ws;
  dim3 blk(256);

  // ---------------- Path A4 layout (persistent ~134.4 MiB) ----------------
  size_t a = 0;
  short* h3p0  = (short*)(ws + a);          a += (size_t)65536 * 768 * 2;   // 96MiB
  // union region: sgTa (32MiB) OVERLAPS pf_sub+pooled+t1+agg (33.03MB);
  // sgT dead after resolve_kernel, the others written after it.
  const size_t ua = a;
  float* sgTa  = (float*)(ws + ua);
  unsigned short* pf_sub = (unsigned short*)(ws + ua);
  short* pooled_a = (short*)(ws + ua + (size_t)17408 * 768 * 2);
  short* t1sa  = (short*)(ws + ua + (size_t)17408 * 768 * 2 + (size_t)1024 * 768 * 2);
  float* agga  = (float*)(ws + ua + (size_t)17408 * 768 * 2 + (size_t)2 * 1024 * 768 * 2);
  a += (size_t)33554432 + (size_t)1703936;  // 32MiB union + slack for pf tail
  short* W2sa  = (short*)(ws + a);          a += (size_t)2 * 256 * 512 * 2;
  short* W3sa  = (short*)(ws + a);          a += (size_t)2 * 512 * 768 * 2;
  short* W4sa  = (short*)(ws + a);          a += (size_t)768 * 768 * 2;
  short* Ws2sa = (short*)(ws + a);          a += (size_t)2 * 768 * 128 * 2;
  short* nW1sa = (short*)(ws + a);          a += (size_t)768 * 768 * 2;
  short* nW2sa = (short*)(ws + a);          a += (size_t)768 * 768 * 2;
  float* bias2a = (float*)(ws + a);         a += 512;
  u64*   canda = (u64*)(ws + a);            a += (size_t)1024 * 32 * 8;
  int*   sela  = (int*)(ws + a);            a += 4096;
  int*   rowlist = (int*)(ws + a);          a += (size_t)17408 * 4;
  int*   rank_a = (int*)(ws + a);           a += 4096;
  a = (a + 255) & ~(size_t)255;
  const size_t tmpA = a;

  // chunk temps (5632 B/row): h2s [0,2048); h1s [2048,3072) / h3c1
  // [2048,3584) (limb1 only, overlaps h1s — dead after L2);
  // scp (K-split partials, 2048 B/row) at [3584, 5632).
  int McA = 0;
  {
    const int mc[4] = {16384, 8192, 4096, 2048};
    for (int ci = 0; ci < 4; ++ci)
      if (tmpA + (size_t)5632 * mc[ci] <= ws_size) { McA = mc[ci]; break; }
  }

  if (McA) {
    // =========================== PATH A4 ===========================
    short* h2s  = (short*)(ws + tmpA);
    short* h1s  = (short*)(ws + tmpA + (size_t)2048 * McA);
    short* h3c1 = (short*)(ws + tmpA + (size_t)2048 * McA);  // overlaps h1s
    float* scp  = (float*)(ws + tmpA + (size_t)3584 * McA);  // [4][128][cm]

    fold_ws2<<<dim3(769), dim3(128), 0, stream>>>(W4, selw, Ws2sa, b4, bias2a);
    presplit_w2x2<<<512, blk, 0, stream>>>(W2, W3, W2sa, W3sa);
    presplit_w1x3<<<512, blk, 0, stream>>>(W4, nW1, nW2, W4sa, nW1sa, nW2sa);

    for (int r0 = 0; r0 < 65536; r0 += McA) {
      const int cm = McA;
      gemm_kernel<128,128,16,256,true ,false,true ,2>
        <<<dim3(cm/128, 2), blk, 0, stream>>>(feats + (size_t)r0 * 32, W1, b1,
                                              nullptr, cm, 256, 32, h1s, cm);
      mfma_gemm<0,2,false><<<dim3(cm/128, 4), blk, 0, stream>>>(
          h1s, W2sa, nullptr, b2, nullptr, h2s, nullptr, nullptr,
          cm, 512, 256, 0, nullptr, 0, 256, cm, cm, 0, 0);
      // L3: limb1 -> slim chunk buffer; limb0 -> persistent plane (only copy)
      mfma_gemm<7,2,false><<<dim3(cm/128, 6), blk, 0, stream>>>(
          h2s, W3sa, nullptr, b3, nullptr, h3c1,
          (unsigned short*)h3p0, nullptr,
          cm, 768, 512, r0, nullptr, 0, 512, cm, cm, 0, 0);
      // K-split scores partials: B limb0 from persistent h3p0 (L3-hot),
      // limb1 from chunk h3c1. grid (m-tiles, 4 K-slices) = 512 blocks.
      mfma_gemm<9,2,false><<<dim3(cm/128, 4), blk, 0, stream>>>(
          Ws2sa, h3p0 + (size_t)r0 * 32, h3c1, nullptr, nullptr, nullptr,
          nullptr, scp, 128, cm, 192, 0, nullptr, 0, 768, 128, 0,
          65536, cm);
      // combine partials + bias2 + gumbel -> sgT
      score_combine<<<dim3(cm/256, 128), blk, 0, stream>>>(
          scp, bias2a, sgTa, cm, r0);
    }

    top_candidates<<<dim3(1024), blk, 0, stream>>>(sgTa, canda);
    resolve_kernel<<<dim3(8), dim3(64), 0, stream>>>(canda, sgTa, sela);
    knn_kernel<false><<<dim3(1024), blk, 0, stream>>>(
        coords, nullptr, sela, nullptr, rowlist);
    // gathered L4 from persistent h3 limb0 (f16), 1-limb value path
    mfma_gemm<4,1,false><<<dim3(136, 6), blk, 0, stream>>>(
        h3p0, W4sa, nullptr, b4, nullptr, nullptr, pf_sub, nullptr,
        17408, 768, 768, 0, rowlist, 0, 768, 65536, 0, 0, 0);
    pool_from_sub<<<dim3(1024), blk, 0, stream>>>(pf_sub, pooled_a);
    mfma_gemm<5,1,false><<<dim3(8, 6), blk, 0, stream>>>(
        pooled_a, nW1sa, nullptr, nb1, nullptr, t1sa, nullptr, nullptr,
        1024, 768, 768, 0, nullptr, 0, 768, 1024, 1024, 0, 0);
    mfma_gemm<1,1,false><<<dim3(8, 6), blk, 0, stream>>>(
        t1sa, nW2sa, nullptr, nb2, nullptr, nullptr, nullptr, agga,
        1024, 768, 768, 0, nullptr, 0, 768, 1024, 0, 0, 0);
    rank_cent<<<dim3(8), dim3(128), 0, stream>>>(coords, sela, rank_a, out);
    token_write<<<dim3(8, 128), dim3(192), 0, stream>>>(
        pf_sub, agga, rank_a, nullptr, out);
    return;
  }

  // =========================== PATH B (fallback) ===========================
  size_t off = 0;
  unsigned short* pf = (unsigned short*)(ws + off); off += (size_t)65536 * 768 * 2;
  float* sgT   = (float*)(ws + off);  off += (size_t)8 * 128 * 8192 * 4;
  short* W2s   = (short*)(ws + off);  off += (size_t)2 * 256 * 512 * 2;
  short* W3s   = (short*)(ws + off);  off += (size_t)2 * 512 * 768 * 2;
  short* W4s   = (short*)(ws + off);  off += (size_t)2 * 768 * 768 * 2;
  short* Ws2s  = (short*)(ws + off);  off += (size_t)2 * 768 * 128 * 2;
  short* nW1s  = (short*)(ws + off);  off += (size_t)2 * 768 * 768 * 2;
  short* nW2s  = (short*)(ws + off);  off += (size_t)2 * 768 * 768 * 2;
  float* bias2 = (float*)(ws + off);  off += 512;
  short* pooled_s = (short*)(ws + off); off += (size_t)2 * 1024 * 768 * 2;
  short* t1s   = (short*)(ws + off);  off += (size_t)2 * 1024 * 768 * 2;
  float* agg   = (float*)(ws + off);  off += (size_t)1024 * 768 * 4;
  u64*   cand  = (u64*)(ws + off);    off += (size_t)1024 * 32 * 8;
  int*   sel   = (int*)(ws + off);    off += 4096;
  int*   rank_g = (int*)(ws + off);   off += 4096;
  off = (off + 255) & ~(size_t)255;
  const size_t tmp_off = off;

  int Mc = 512;
  const int mcand[6] = {16384, 8192, 4096, 2048, 1024, 512};
  for (int ci = 0; ci < 6; ++ci) {
    if (tmp_off + (size_t)5120 * mcand[ci] <= ws_size) { Mc = mcand[ci]; break; }
  }
  short* tA = (short*)(ws + tmp_off);                       // h2s (2048 B/row)
  short* tB = (short*)(ws + tmp_off + (size_t)2048 * Mc);   // h1s/h3s (3072 B/row)
  float* scc = (float*)tA;  // alias: h2s dead after L3

  fold_ws2<<<dim3(769), dim3(128), 0, stream>>>(W4, selw, Ws2s, b4, bias2);
  presplit_w2x2<<<512, blk, 0, stream>>>(W2, W3, W2s, W3s);
  presplit_w2<<<256, blk, 0, stream>>>(W4, W4s, 768, 768);
  presplit_w2<<<256, blk, 0, stream>>>(nW1, nW1s, 768, 768);
  presplit_w2<<<256, blk, 0, stream>>>(nW2, nW2s, 768, 768);

  for (int r0 = 0; r0 < 65536; r0 += Mc) {
    const int cm = (65536 - r0 < Mc) ? (65536 - r0) : Mc;
    short* h1s = tB;
    short* h2s = tA;
    short* h3s = tB;  // alias: h1s dead after L2
    gemm_kernel<128,128,16,256,true ,false,true ,2>
      <<<dim3(cm/128, 2), blk, 0, stream>>>(feats + (size_t)r0 * 32, W1, b1,
                                            nullptr, cm, 256, 32, h1s, cm);
    mfma_gemm<0,2,false><<<dim3(cm/128, 4), blk, 0, stream>>>(
        h1s, W2s, nullptr, b2, nullptr, h2s, nullptr, nullptr,
        cm, 512, 256, 0, nullptr, 0, 256, cm, cm, 0, 0);
    mfma_gemm<0,2,false><<<dim3(cm/128, 6), blk, 0, stream>>>(
        h2s, W3s, nullptr, b3, nullptr, h3s, nullptr, nullptr,
        cm, 768, 512, 0, nullptr, 0, 512, cm, cm, 0, 0);
    mfma_gemm<2,2,false><<<dim3(cm/128, 7), blk, 0, stream>>>(
        h3s, W4s, Ws2s, b4, bias2, nullptr, pf, scc,
        cm, 768, 768, r0, nullptr, 0, 768, cm, 0, 0, 0);
    gumbel_transpose<<<dim3(cm/32, 4), dim3(32, 8), 0, stream>>>(scc, sgT, r0);
  }

  top_candidates<<<dim3(1024), blk, 0, stream>>>(sgT, cand);
  resolve_kernel<<<dim3(8), dim3(64), 0, stream>>>(cand, sgT, sel);
  knn_kernel<true ><<<dim3(1024), blk, 0, stream>>>(
      coords, (const __hip_bfloat16*)pf, sel, pooled_s, nullptr);
  mfma_gemm<0,2,false><<<dim3(8, 6), blk, 0, stream>>>(
      pooled_s, nW1s, nullptr, nb1, nullptr, t1s, nullptr, nullptr,
      1024, 768, 768, 0, nullptr, 0, 768, 1024, 1024, 0, 0);
  mfma_gemm<1,2,false><<<dim3(8, 6), blk, 0, stream>>>(
      t1s, nW2s, nullptr, nb2, nullptr, nullptr, nullptr, agg,
      1024, 768, 768, 0, nullptr, 0, 768, 1024, 0, 0, 0);
  rank_cent<<<dim3(8), dim3(128), 0, stream>>>(coords, sel, rank_g, out);
  token_write<<<dim3(8, 128), dim3(192), 0, stream>>>(
      pf, agg, rank_g, sel, out);
}